// Round 1
// baseline (992.108 us; speedup 1.0000x reference)
//
#include <hip/hip_runtime.h>
#include <cmath>

#define S_ 1024
#define B_ 8
#define H_ 512
#define S2_ 1022
#define M_ (B_*S2_)   // 8176

typedef __attribute__((ext_vector_type(8))) short bf16x8;
typedef __attribute__((ext_vector_type(4))) float f32x4;
typedef __attribute__((ext_vector_type(4))) unsigned int u32x4;
typedef __attribute__((ext_vector_type(2))) unsigned int u32x2;

__device__ __forceinline__ unsigned short f2bf(float f){
  unsigned int u = __float_as_uint(f);
  return (unsigned short)((u + 0x7fffu + ((u>>16)&1u)) >> 16);
}

__device__ __forceinline__ void glds16(const void* g, void* l){
  __builtin_amdgcn_global_load_lds((const __attribute__((address_space(1))) unsigned int*)g,
                                   (__attribute__((address_space(3))) unsigned int*)l, 16, 0, 0);
}

// ---------------------------------------------------------------- prep: build X = [f[:-2], bk[2:]] as bf16 (M x 1024)
__global__ __launch_bounds__(256) void lma_prep_x(const float* __restrict__ hidden,
                                                  unsigned short* __restrict__ Xb){
  int m = blockIdx.x; int dq = threadIdx.x * 4;
  int b = m / S2_, s = m - b * S2_;
  int srow = (dq < 512) ? s : (s + 2);
  const float* src = hidden + ((size_t)srow * B_ + b) * 1024 + dq;
  f32x4 v = *(const f32x4*)src;
  union { u32x2 u; unsigned short s4[4]; } pk;
  #pragma unroll
  for (int j = 0; j < 4; j++) pk.s4[j] = f2bf(v[j]);
  *(u32x2*)&Xb[(size_t)m * 1024 + dq] = pk.u;
}

// ---------------------------------------------------------------- weight transpose+cast: W(K x N) f32 -> WT(N x K) bf16
__global__ __launch_bounds__(256) void lma_transpose_w(const float* __restrict__ W,
                                                       unsigned short* __restrict__ WT,
                                                       int K, int N){
  __shared__ float t[32][33];
  int kb = blockIdx.x * 32, nb = blockIdx.y * 32;
  int tx = threadIdx.x & 31, ty = threadIdx.x >> 5;
  #pragma unroll
  for (int i = ty; i < 32; i += 8) t[i][tx] = W[(size_t)(kb + i) * N + nb + tx];
  __syncthreads();
  #pragma unroll
  for (int i = ty; i < 32; i += 8) WT[(size_t)(nb + i) * K + kb + tx] = f2bf(t[tx][i]);
}

// ---------------------------------------------------------------- GEMM: C(MxN) = A(MxK,bf16,lda) * Bt(NxK,bf16)^T + bias
// modes: 0 bf16 bias | 1 bf16 (bias)*0.125 | 2 bf16 bias+gelu | 3 f32 bias | 4 f32 bias, row-remapped (s*B+b) store
__global__ __launch_bounds__(256) void lma_gemm_bt(
    const unsigned short* __restrict__ A, int lda,
    const unsigned short* __restrict__ Bt,
    const float* __restrict__ bias,
    void* __restrict__ Cout, int ldc,
    int M, int N, int K, int mode)
{
  __shared__ unsigned short Al[128*32];
  __shared__ unsigned short Bl[128*32];
  const int tid = threadIdx.x;
  const int w = tid >> 6, lane = tid & 63, quad = lane >> 4, l16 = lane & 15;
  const int m0 = blockIdx.y * 128, n0 = blockIdx.x * 128;
  const int wm = (w >> 1) * 64, wn = (w & 1) * 64;

  f32x4 acc[4][4];
  #pragma unroll
  for (int i = 0; i < 4; i++)
    #pragma unroll
    for (int f = 0; f < 4; f++) acc[i][f] = f32x4{0.f,0.f,0.f,0.f};

  const int srow = lane >> 2;        // 0..15
  const int spc  = (lane & 3) * 8;   // element offset in k

  for (int k0 = 0; k0 < K; k0 += 32) {
    #pragma unroll
    for (int c = 0; c < 2; c++) {
      int ra = w*32 + c*16 + srow;
      int ga = m0 + ra; if (ga > M-1) ga = M-1;
      glds16(A + (size_t)ga * lda + k0 + spc, &Al[(w*32 + c*16) * 32]);
      int gb = n0 + ra; if (gb > N-1) gb = N-1;
      glds16(Bt + (size_t)gb * K + k0 + spc, &Bl[(w*32 + c*16) * 32]);
    }
    __syncthreads();
    bf16x8 af[4], bfr[4];
    #pragma unroll
    for (int i = 0; i < 4; i++) af[i]  = *(const bf16x8*)&Al[(wm + i*16 + l16)*32 + quad*8];
    #pragma unroll
    for (int f = 0; f < 4; f++) bfr[f] = *(const bf16x8*)&Bl[(wn + f*16 + l16)*32 + quad*8];
    #pragma unroll
    for (int i = 0; i < 4; i++)
      #pragma unroll
      for (int f = 0; f < 4; f++)
        acc[i][f] = __builtin_amdgcn_mfma_f32_16x16x32_bf16(af[i], bfr[f], acc[i][f], 0, 0, 0);
    __syncthreads();
  }

  #pragma unroll
  for (int f = 0; f < 4; f++) {
    int col = n0 + wn + f*16 + l16;
    float bv = bias ? bias[col] : 0.f;
    #pragma unroll
    for (int i = 0; i < 4; i++) {
      #pragma unroll
      for (int r = 0; r < 4; r++) {
        int row = m0 + wm + i*16 + quad*4 + r;
        if (row < M) {
          float v = acc[i][f][r] + bv;
          if (mode == 2) v = 0.5f * v * (1.f + erff(v * 0.70710678118654752f));
          else if (mode == 1) v *= 0.125f;
          if (mode <= 2) ((unsigned short*)Cout)[(size_t)row * ldc + col] = f2bf(v);
          else if (mode == 3) ((float*)Cout)[(size_t)row * ldc + col] = v;
          else {
            int sr = row % S2_, br = row / S2_;
            ((float*)Cout)[((size_t)sr * B_ + br) * ldc + col] = v;
          }
        }
      }
    }
  }
}

// ---------------------------------------------------------------- block reduction helper (sum, sumsq) over 256 threads
__device__ __forceinline__ void lma_red2(float& s, float& sq){
  __shared__ float red[16];
  #pragma unroll
  for (int msk = 1; msk < 64; msk <<= 1){ s += __shfl_xor(s, msk); sq += __shfl_xor(sq, msk); }
  int w = threadIdx.x >> 6;
  if ((threadIdx.x & 63) == 0){ red[w] = s; red[8 + w] = sq; }
  __syncthreads();
  s  = red[0] + red[1] + red[2] + red[3];
  sq = red[8] + red[9] + red[10] + red[11];
}

// ---------------------------------------------------------------- LN: in f32 rows (M x D) -> bf16 out OR f32 out (in-place ok)
__global__ __launch_bounds__(256) void lma_ln(const float* __restrict__ in,
                                              const float* __restrict__ g, const float* __restrict__ bb,
                                              int D, unsigned short* __restrict__ obf, float* __restrict__ of32){
  int row = blockIdx.x, t = threadIdx.x;
  const float* x = in + (size_t)row * D;
  float s = 0.f, sq = 0.f;
  for (int d = t; d < D; d += 256){ float v = x[d]; s += v; sq += v * v; }
  lma_red2(s, sq);
  float mean = s / D;
  float var = sq / D - mean * mean;
  float rstd = rsqrtf(fmaxf(var, 0.f) + 1e-12f);
  if (obf) {
    for (int d = t; d < D; d += 256) {
      float v = (x[d] - mean) * rstd * g[d] + bb[d];
      obf[(size_t)row * D + d] = f2bf(v);
    }
  } else {
    for (int d = t; d < D; d += 256) {
      float v = (x[d] - mean) * rstd * g[d] + bb[d];
      of32[(size_t)row * D + d] = v;
    }
  }
}

// ---------------------------------------------------------------- attn LN: LN(residual(hidden) + [pf, pb]) -> bf16 (M x 1024)
__global__ __launch_bounds__(256) void lma_attn_ln(const float* __restrict__ pf, const float* __restrict__ pb,
                                                   const float* __restrict__ hidden,
                                                   const float* __restrict__ g, const float* __restrict__ bb,
                                                   unsigned short* __restrict__ out){
  int m = blockIdx.x, t = threadIdx.x;
  int b = m / S2_, s = m - b * S2_;
  const float* hf = hidden + ((size_t)s       * B_ + b) * 1024;
  const float* hb = hidden + ((size_t)(s + 2) * B_ + b) * 1024;
  float v[4]; float sum = 0.f, sq = 0.f;
  #pragma unroll
  for (int j = 0; j < 4; j++){
    int d = t + j * 256;
    float x = (d < 512) ? (pf[(size_t)m * 512 + d] + hf[d])
                        : (pb[(size_t)m * 512 + (d - 512)] + hb[d]);
    v[j] = x; sum += x; sq += x * x;
  }
  lma_red2(sum, sq);
  float mean = sum / 1024.f;
  float var = sq / 1024.f - mean * mean;
  float rstd = rsqrtf(fmaxf(var, 0.f) + 1e-12f);
  #pragma unroll
  for (int j = 0; j < 4; j++){
    int d = t + j * 256;
    float y = (v[j] - mean) * rstd * g[d] + bb[d];
    out[(size_t)m * 1024 + d] = f2bf(y);
  }
}

// ---------------------------------------------------------------- flash attention, 8 heads, dh=64, online softmax
// grid (16 qtiles, 8 heads, 8 batch), block 256 (4 waves x 16 q-rows)
__global__ __launch_bounds__(256) void lma_attn(const unsigned short* __restrict__ Q,
                                                const unsigned short* __restrict__ Kx,
                                                const unsigned short* __restrict__ Vx,
                                                unsigned short* __restrict__ CTX,
                                                const int* __restrict__ lens, int backward){
  __shared__ unsigned short Kl[32*64];
  __shared__ unsigned short VTl[64*32];
  __shared__ unsigned short Pl[4][16*32];

  const int tid = threadIdx.x;
  const int w = tid >> 6, lane = tid & 63, quad = lane >> 4, l16 = lane & 15;
  const int qt = blockIdx.x, h = blockIdx.y, b = blockIdx.z;
  const int L2 = lens[b] - 2;
  const int q0wg = qt * 64;
  const int q0 = q0wg + w * 16;
  const size_t base = ((size_t)b * S2_) * 512 + h * 64;

  bf16x8 qf[2];
  {
    int qm = q0 + l16; if (qm > S2_ - 1) qm = S2_ - 1;
    const unsigned short* qp = Q + base + (size_t)qm * 512 + quad * 8;
    qf[0] = *(const bf16x8*)(qp);
    qf[1] = *(const bf16x8*)(qp + 32);
  }

  float mi[4], li[4];
  #pragma unroll
  for (int r = 0; r < 4; r++){ mi[r] = -3e38f; li[r] = 0.f; }
  f32x4 oacc[4];
  #pragma unroll
  for (int f = 0; f < 4; f++) oacc[f] = f32x4{0.f,0.f,0.f,0.f};

  const int trow = tid >> 3;       // 0..31 key row within tile
  const int tpc  = (tid & 7) * 8;  // 0..56 d offset

  // key-tile range pruning from mask structure
  int klo = 0, khi = S2_ - 1;
  if (q0wg + 63 < L2) {
    if (!backward) khi = q0wg + 63;
    else { klo = q0wg & ~31; khi = L2 - 1; }
  }

  for (int kt0 = klo; kt0 <= khi; kt0 += 32) {
    {
      int kr = kt0 + trow; if (kr > S2_ - 1) kr = S2_ - 1;
      u32x4 kv = *(const u32x4*)(Kx + base + (size_t)kr * 512 + tpc);
      *(u32x4*)&Kl[trow * 64 + tpc] = kv;
      union { u32x4 v; unsigned short s[8]; } uv;
      uv.v = *(const u32x4*)(Vx + base + (size_t)kr * 512 + tpc);
      #pragma unroll
      for (int j = 0; j < 8; j++) VTl[(tpc + j) * 32 + trow] = uv.s[j];
    }
    __syncthreads();

    f32x4 sfr[2];
    #pragma unroll
    for (int sub = 0; sub < 2; sub++) {
      bf16x8 kf0 = *(const bf16x8*)&Kl[(sub*16 + l16)*64 + quad*8];
      bf16x8 kf1 = *(const bf16x8*)&Kl[(sub*16 + l16)*64 + 32 + quad*8];
      f32x4 s = f32x4{0.f,0.f,0.f,0.f};
      s = __builtin_amdgcn_mfma_f32_16x16x32_bf16(qf[0], kf0, s, 0, 0, 0);
      s = __builtin_amdgcn_mfma_f32_16x16x32_bf16(qf[1], kf1, s, 0, 0, 0);
      sfr[sub] = s;
    }

    #pragma unroll
    for (int r = 0; r < 4; r++) {
      int qg = q0 + quad * 4 + r;
      #pragma unroll
      for (int sub = 0; sub < 2; sub++) {
        int kg = kt0 + sub * 16 + l16;
        bool ok;
        if (!backward) ok = (kg < S2_) && ((qg >= L2) || (kg <= qg));
        else           ok = (kg < S2_) && ((qg >= L2) || ((kg >= qg) && (kg < L2)));
        if (!ok) sfr[sub][r] = -3e38f;
      }
      float mx = fmaxf(sfr[0][r], sfr[1][r]);
      #pragma unroll
      for (int d = 1; d < 16; d <<= 1) mx = fmaxf(mx, __shfl_xor(mx, d));
      float mn = fmaxf(mi[r], mx);
      float alpha = __expf(mi[r] - mn);
      float p0 = __expf(sfr[0][r] - mn);
      float p1 = __expf(sfr[1][r] - mn);
      float rs = p0 + p1;
      #pragma unroll
      for (int d = 1; d < 16; d <<= 1) rs += __shfl_xor(rs, d);
      li[r] = li[r] * alpha + rs;
      mi[r] = mn;
      #pragma unroll
      for (int f = 0; f < 4; f++) oacc[f][r] *= alpha;
      Pl[w][(quad*4 + r)*32 + l16]      = f2bf(p0);
      Pl[w][(quad*4 + r)*32 + 16 + l16] = f2bf(p1);
    }

    // P (C-layout) -> A-operand layout via per-wave LDS region (wave-internal, DS ops are in-order)
    bf16x8 pf = *(const bf16x8*)&Pl[w][l16*32 + quad*8];
    #pragma unroll
    for (int f = 0; f < 4; f++) {
      bf16x8 vf = *(const bf16x8*)&VTl[(f*16 + l16)*32 + quad*8];
      oacc[f] = __builtin_amdgcn_mfma_f32_16x16x32_bf16(pf, vf, oacc[f], 0, 0, 0);
    }
    __syncthreads();
  }

  #pragma unroll
  for (int f = 0; f < 4; f++) {
    #pragma unroll
    for (int r = 0; r < 4; r++) {
      int row = q0 + quad * 4 + r;
      if (row < S2_) {
        float v = oacc[f][r] / li[r];
        CTX[base + (size_t)row * 512 + f*16 + l16] = f2bf(v);
      }
    }
  }
}

// ----------------------------------------------------------------
extern "C" void kernel_launch(void* const* d_in, const int* in_sizes, int n_in,
                              void* d_out, int out_size, void* d_ws, size_t ws_size,
                              hipStream_t stream)
{
  const float* hidden = (const float*)d_in[0];
  const int*   lens   = (const int*)d_in[1];
  const float* fw[14]; for (int i = 0; i < 14; i++) fw[i] = (const float*)d_in[2 + i];
  const float* bw[14]; for (int i = 0; i < 14; i++) bw[i] = (const float*)d_in[16 + i];
  const float* attn_g = (const float*)d_in[30];
  const float* attn_b = (const float*)d_in[31];
  const float* o_w1 = (const float*)d_in[32];
  const float* o_b1 = (const float*)d_in[33];
  const float* o_w2 = (const float*)d_in[34];
  const float* o_b2 = (const float*)d_in[35];
  const float* o_lng = (const float*)d_in[36];
  const float* o_lnb = (const float*)d_in[37];
  // per-branch weight index map: 0 w1,1 b1,2 w2,3 b2,4 lng,5 lnb,6 qw,7 qb,8 kw,9 kb,10 vw,11 vb,12 ow,13 ob

  char* ws = (char*)d_ws;
  size_t off = 0;
  auto alloc = [&](size_t bytes)->char* {
    off = (off + 255) & ~(size_t)255;
    char* p = ws + off; off += bytes; return p;
  };

  unsigned short* fw1t = (unsigned short*)alloc((size_t)1024*1024*2);
  unsigned short* fw2t = (unsigned short*)alloc((size_t)512*1024*2);
  unsigned short* fqt  = (unsigned short*)alloc((size_t)512*512*2);
  unsigned short* fkt  = (unsigned short*)alloc((size_t)512*512*2);
  unsigned short* fvt  = (unsigned short*)alloc((size_t)512*512*2);
  unsigned short* fot  = (unsigned short*)alloc((size_t)512*512*2);
  unsigned short* bw1t = (unsigned short*)alloc((size_t)1024*1024*2);
  unsigned short* bw2t = (unsigned short*)alloc((size_t)512*1024*2);
  unsigned short* bqt  = (unsigned short*)alloc((size_t)512*512*2);
  unsigned short* bkt  = (unsigned short*)alloc((size_t)512*512*2);
  unsigned short* bvt  = (unsigned short*)alloc((size_t)512*512*2);
  unsigned short* bot  = (unsigned short*)alloc((size_t)512*512*2);
  unsigned short* ow1t = (unsigned short*)alloc((size_t)1024*1024*2);
  unsigned short* ow2t = (unsigned short*)alloc((size_t)1024*1024*2);

  unsigned short* Xb = (unsigned short*)alloc((size_t)M_*1024*2); // also attn-LN output later
  unsigned short* H1 = (unsigned short*)alloc((size_t)M_*1024*2);
  float*          T1 = (float*)alloc((size_t)M_*512*4);
  unsigned short* LQ = (unsigned short*)alloc((size_t)M_*512*2);
  unsigned short* Qb = (unsigned short*)alloc((size_t)M_*512*2);
  unsigned short* Kb = (unsigned short*)alloc((size_t)M_*512*2);
  unsigned short* Vb = (unsigned short*)alloc((size_t)M_*512*2);
  unsigned short* CT = (unsigned short*)alloc((size_t)M_*512*2);
  float*          PF = (float*)alloc((size_t)M_*512*4);
  float*          PB = (float*)alloc((size_t)M_*512*4);

  auto T = [&](const float* W, unsigned short* WT, int K, int N){
    lma_transpose_w<<<dim3(K/32, N/32), 256, 0, stream>>>(W, WT, K, N);
  };
  auto G = [&](const unsigned short* A, int lda, const unsigned short* Bt,
               const float* bias, void* C, int ldc, int N, int K, int mode){
    lma_gemm_bt<<<dim3(N/128, (M_ + 127)/128), 256, 0, stream>>>(A, lda, Bt, bias, C, ldc, M_, N, K, mode);
  };

  lma_prep_x<<<M_, 256, 0, stream>>>(hidden, Xb);

  T(fw[0], fw1t, 1024, 1024); T(fw[2], fw2t, 1024, 512);
  T(fw[6], fqt, 512, 512); T(fw[8], fkt, 512, 512); T(fw[10], fvt, 512, 512); T(fw[12], fot, 512, 512);
  T(bw[0], bw1t, 1024, 1024); T(bw[2], bw2t, 1024, 512);
  T(bw[6], bqt, 512, 512); T(bw[8], bkt, 512, 512); T(bw[10], bvt, 512, 512); T(bw[12], bot, 512, 512);
  T(o_w1, ow1t, 1024, 1024); T(o_w2, ow2t, 1024, 1024);

  // ---- forward branch
  G(Xb, 1024, fw1t, fw[1], H1, 1024, 1024, 1024, 2);          // gelu FFN1 -> bf16
  G(H1, 1024, fw2t, fw[3], T1, 512, 512, 1024, 3);            // FFN2 -> f32
  lma_ln<<<M_, 256, 0, stream>>>(T1, fw[4], fw[5], 512, LQ, nullptr);
  G(LQ, 512, fqt, fw[7], Qb, 512, 512, 512, 1);               // Q (scaled 1/8)
  G(Xb, 1024, fkt, fw[9], Kb, 512, 512, 512, 0);              // K from f kv
  G(Xb, 1024, fvt, fw[11], Vb, 512, 512, 512, 0);             // V
  lma_attn<<<dim3(16, 8, 8), 256, 0, stream>>>(Qb, Kb, Vb, CT, lens, 0);
  G(CT, 512, fot, fw[13], PF, 512, 512, 512, 3);              // out proj -> f32

  // ---- backward branch
  G(Xb, 1024, bw1t, bw[1], H1, 1024, 1024, 1024, 2);
  G(H1, 1024, bw2t, bw[3], T1, 512, 512, 1024, 3);
  lma_ln<<<M_, 256, 0, stream>>>(T1, bw[4], bw[5], 512, LQ, nullptr);
  G(LQ, 512, bqt, bw[7], Qb, 512, 512, 512, 1);
  G(Xb + 512, 1024, bkt, bw[9], Kb, 512, 512, 512, 0);        // K from b kv (second half cols)
  G(Xb + 512, 1024, bvt, bw[11], Vb, 512, 512, 512, 0);
  lma_attn<<<dim3(16, 8, 8), 256, 0, stream>>>(Qb, Kb, Vb, CT, lens, 1);
  G(CT, 512, bot, bw[13], PB, 512, 512, 512, 3);

  // ---- residual + attn LN (writes into Xb region as bf16)
  lma_attn_ln<<<M_, 256, 0, stream>>>(PF, PB, hidden, attn_g, attn_b, Xb);

  // ---- output FFN + final LN (GEMM stores remapped (s*B+b) rows straight into d_out; LN in place)
  G(Xb, 1024, ow1t, o_b1, H1, 1024, 1024, 1024, 2);
  G(H1, 1024, ow2t, o_b2, (float*)d_out, 1024, 1024, 1024, 4);
  lma_ln<<<M_, 256, 0, stream>>>((float*)d_out, o_lng, o_lnb, 1024, nullptr, (float*)d_out);
}

// Round 4
// 955.937 us; speedup vs baseline: 1.0378x; 1.0378x over previous
//
#include <hip/hip_runtime.h>
#include <cmath>

#define S_ 1024
#define B_ 8
#define H_ 512
#define S2_ 1022
#define M_ (B_*S2_)   // 8176

typedef __attribute__((ext_vector_type(8))) short bf16x8;
typedef __attribute__((ext_vector_type(4))) float f32x4;
typedef __attribute__((ext_vector_type(4))) unsigned int u32x4;
typedef __attribute__((ext_vector_type(2))) unsigned int u32x2;

__device__ __forceinline__ unsigned short f2bf(float f){
  unsigned int u = __float_as_uint(f);
  return (unsigned short)((u + 0x7fffu + ((u>>16)&1u)) >> 16);
}

__device__ __forceinline__ void glds16(const void* g, void* l){
  __builtin_amdgcn_global_load_lds((const __attribute__((address_space(1))) unsigned int*)g,
                                   (__attribute__((address_space(3))) unsigned int*)l, 16, 0, 0);
}

// ---------------------------------------------------------------- prep: build X = [f[:-2], bk[2:]] as bf16 (M x 1024)
__global__ __launch_bounds__(256) void lma_prep_x(const float* __restrict__ hidden,
                                                  unsigned short* __restrict__ Xb){
  int m = blockIdx.x; int dq = threadIdx.x * 4;
  int b = m / S2_, s = m - b * S2_;
  int srow = (dq < 512) ? s : (s + 2);
  const float* src = hidden + ((size_t)srow * B_ + b) * 1024 + dq;
  f32x4 v = *(const f32x4*)src;
  union { u32x2 u; unsigned short s4[4]; } pk;
  #pragma unroll
  for (int j = 0; j < 4; j++) pk.s4[j] = f2bf(v[j]);
  *(u32x2*)&Xb[(size_t)m * 1024 + dq] = pk.u;
}

// ---------------------------------------------------------------- batched weight transpose+cast: W(K x N) f32 -> WT(N x K) bf16
struct TPack {
  const float* src[14];
  unsigned short* dst[14];
  int K[14];
  int N[14];
};
__global__ __launch_bounds__(256) void lma_transpose_all(TPack p){
  int idx = blockIdx.z;
  int K = p.K[idx], N = p.N[idx];
  int kb = blockIdx.x * 32, nb = blockIdx.y * 32;
  if (kb >= K || nb >= N) return;
  const float* W = p.src[idx];
  unsigned short* WT = p.dst[idx];
  __shared__ float t[32][33];
  int tx = threadIdx.x & 31, ty = threadIdx.x >> 5;
  #pragma unroll
  for (int i = ty; i < 32; i += 8) t[i][tx] = W[(size_t)(kb + i) * N + nb + tx];
  __syncthreads();
  #pragma unroll
  for (int i = ty; i < 32; i += 8) WT[(size_t)(nb + i) * K + kb + tx] = f2bf(t[tx][i]);
}

// ---------------------------------------------------------------- V (M x 512 bf16) -> VT[b][h][d][s] (rows padded to 1024)
// Padding columns s in [S2_, 1024) are ZEROED — VT aliases a buffer whose
// stale fp32 halves can reinterpret as bf16 NaN; masked keys (p=0) would then
// poison the PV MFMA with 0*NaN. (Round 2/3 NaN root cause.)
__global__ __launch_bounds__(256) void lma_vt(const unsigned short* __restrict__ V,
                                              unsigned short* __restrict__ VT){
  __shared__ unsigned short t[32][34];
  int s0 = blockIdx.x * 32, c0 = blockIdx.y * 32, b = blockIdx.z;
  int tx = threadIdx.x & 31, ty = threadIdx.x >> 5;
  #pragma unroll
  for (int i = ty; i < 32; i += 8){
    int s = s0 + i; if (s > S2_-1) s = S2_-1;
    t[i][tx] = V[((size_t)b * S2_ + s) * 512 + c0 + tx];
  }
  __syncthreads();
  int s = s0 + tx;
  #pragma unroll
  for (int i = ty; i < 32; i += 8){
    int c = c0 + i, h = c >> 6, d = c & 63;
    VT[(((size_t)b * 8 + h) * 64 + d) * 1024 + s] = (s < S2_) ? t[tx][i] : (unsigned short)0;
  }
}

// ---------------------------------------------------------------- GEMM: C(MxN) = A(MxK,bf16,lda) * Bt(NxK,bf16)^T + bias
// modes: 0 bf16 bias | 1 bf16 (bias)*0.125 | 2 bf16 bias+gelu | 3 f32 bias | 4 f32 bias, row-remapped (s*B+b) store
__global__ __launch_bounds__(256) void lma_gemm_bt(
    const unsigned short* __restrict__ A, int lda,
    const unsigned short* __restrict__ Bt,
    const float* __restrict__ bias,
    void* __restrict__ Cout, int ldc,
    int M, int N, int K, int mode)
{
  __shared__ unsigned short Al[128*32];
  __shared__ unsigned short Bl[128*32];
  const int tid = threadIdx.x;
  const int w = tid >> 6, lane = tid & 63, quad = lane >> 4, l16 = lane & 15;
  const int m0 = blockIdx.y * 128, n0 = blockIdx.x * 128;
  const int wm = (w >> 1) * 64, wn = (w & 1) * 64;

  f32x4 acc[4][4];
  #pragma unroll
  for (int i = 0; i < 4; i++)
    #pragma unroll
    for (int f = 0; f < 4; f++) acc[i][f] = f32x4{0.f,0.f,0.f,0.f};

  const int srow = lane >> 2;        // 0..15
  const int spc  = (lane & 3) * 8;   // element offset in k

  for (int k0 = 0; k0 < K; k0 += 32) {
    #pragma unroll
    for (int c = 0; c < 2; c++) {
      int ra = w*32 + c*16 + srow;
      int ga = m0 + ra; if (ga > M-1) ga = M-1;
      glds16(A + (size_t)ga * lda + k0 + spc, &Al[(w*32 + c*16) * 32]);
      int gb = n0 + ra; if (gb > N-1) gb = N-1;
      glds16(Bt + (size_t)gb * K + k0 + spc, &Bl[(w*32 + c*16) * 32]);
    }
    __syncthreads();
    bf16x8 af[4], bfr[4];
    #pragma unroll
    for (int i = 0; i < 4; i++) af[i]  = *(const bf16x8*)&Al[(wm + i*16 + l16)*32 + quad*8];
    #pragma unroll
    for (int f = 0; f < 4; f++) bfr[f] = *(const bf16x8*)&Bl[(wn + f*16 + l16)*32 + quad*8];
    #pragma unroll
    for (int i = 0; i < 4; i++)
      #pragma unroll
      for (int f = 0; f < 4; f++)
        acc[i][f] = __builtin_amdgcn_mfma_f32_16x16x32_bf16(af[i], bfr[f], acc[i][f], 0, 0, 0);
    __syncthreads();
  }

  #pragma unroll
  for (int f = 0; f < 4; f++) {
    int col = n0 + wn + f*16 + l16;
    float bv = bias ? bias[col] : 0.f;
    #pragma unroll
    for (int i = 0; i < 4; i++) {
      #pragma unroll
      for (int r = 0; r < 4; r++) {
        int row = m0 + wm + i*16 + quad*4 + r;
        if (row < M) {
          float v = acc[i][f][r] + bv;
          if (mode == 2) v = 0.5f * v * (1.f + erff(v * 0.70710678118654752f));
          else if (mode == 1) v *= 0.125f;
          if (mode <= 2) ((unsigned short*)Cout)[(size_t)row * ldc + col] = f2bf(v);
          else if (mode == 3) ((float*)Cout)[(size_t)row * ldc + col] = v;
          else {
            int sr = row % S2_, br = row / S2_;
            ((float*)Cout)[((size_t)sr * B_ + br) * ldc + col] = v;
          }
        }
      }
    }
  }
}

// ---------------------------------------------------------------- block reduction helper (sum, sumsq) over 256 threads
__device__ __forceinline__ void lma_red2(float& s, float& sq){
  __shared__ float red[16];
  #pragma unroll
  for (int msk = 1; msk < 64; msk <<= 1){ s += __shfl_xor(s, msk); sq += __shfl_xor(sq, msk); }
  int w = threadIdx.x >> 6;
  if ((threadIdx.x & 63) == 0){ red[w] = s; red[8 + w] = sq; }
  __syncthreads();
  s  = red[0] + red[1] + red[2] + red[3];
  sq = red[8] + red[9] + red[10] + red[11];
}

// ---------------------------------------------------------------- LN: in f32 rows (M x D) -> bf16 out OR f32 out (in-place ok)
__global__ __launch_bounds__(256) void lma_ln(const float* __restrict__ in,
                                              const float* __restrict__ g, const float* __restrict__ bb,
                                              int D, unsigned short* __restrict__ obf, float* __restrict__ of32){
  int row = blockIdx.x, t = threadIdx.x;
  const float* x = in + (size_t)row * D;
  float s = 0.f, sq = 0.f;
  for (int d = t; d < D; d += 256){ float v = x[d]; s += v; sq += v * v; }
  lma_red2(s, sq);
  float mean = s / D;
  float var = sq / D - mean * mean;
  float rstd = rsqrtf(fmaxf(var, 0.f) + 1e-12f);
  if (obf) {
    for (int d = t; d < D; d += 256) {
      float v = (x[d] - mean) * rstd * g[d] + bb[d];
      obf[(size_t)row * D + d] = f2bf(v);
    }
  } else {
    for (int d = t; d < D; d += 256) {
      float v = (x[d] - mean) * rstd * g[d] + bb[d];
      of32[(size_t)row * D + d] = v;
    }
  }
}

// ---------------------------------------------------------------- attn LN: LN(residual(hidden) + [pf, pb]) -> bf16 (M x 1024)
__global__ __launch_bounds__(256) void lma_attn_ln(const float* __restrict__ pf, const float* __restrict__ pb,
                                                   const float* __restrict__ hidden,
                                                   const float* __restrict__ g, const float* __restrict__ bb,
                                                   unsigned short* __restrict__ out){
  int m = blockIdx.x, t = threadIdx.x;
  int b = m / S2_, s = m - b * S2_;
  const float* hf = hidden + ((size_t)s       * B_ + b) * 1024;
  const float* hb = hidden + ((size_t)(s + 2) * B_ + b) * 1024;
  float v[4]; float sum = 0.f, sq = 0.f;
  #pragma unroll
  for (int j = 0; j < 4; j++){
    int d = t + j * 256;
    float x = (d < 512) ? (pf[(size_t)m * 512 + d] + hf[d])
                        : (pb[(size_t)m * 512 + (d - 512)] + hb[d]);
    v[j] = x; sum += x; sq += x * x;
  }
  lma_red2(sum, sq);
  float mean = sum / 1024.f;
  float var = sq / 1024.f - mean * mean;
  float rstd = rsqrtf(fmaxf(var, 0.f) + 1e-12f);
  #pragma unroll
  for (int j = 0; j < 4; j++){
    int d = t + j * 256;
    float y = (v[j] - mean) * rstd * g[d] + bb[d];
    out[(size_t)m * 1024 + d] = f2bf(y);
  }
}

// ---------------------------------------------------------------- flash attention v2: S^T orientation, barrier-free
// grid (16 qtiles of 64, 8 heads, 8 batch), block 256 = 4 waves x 16 q-cols
// Each lane owns ONE q column; K/Q/VT fragments loaded straight from global.
// P-scratch stride = 80 shorts (160 B, multiple of 16 B so b128 reads stay
// aligned; 2-way bank aliasing = free).
#define PSTR 80
__global__ __launch_bounds__(256) void lma_attn2(const unsigned short* __restrict__ Q,
                                                 const unsigned short* __restrict__ Kx,
                                                 const unsigned short* __restrict__ VT,
                                                 unsigned short* __restrict__ CTX,
                                                 const int* __restrict__ lens, int backward){
  __shared__ __align__(16) unsigned short Pl[4][16*PSTR];

  const int tid = threadIdx.x;
  const int w = tid >> 6, lane = tid & 63, quad = lane >> 4, l16 = lane & 15;
  const int qt = blockIdx.x, h = blockIdx.y, b = blockIdx.z;
  const int L2 = lens[b] - 2;
  const int q0wg = qt * 64;
  const int q0 = q0wg + w * 16;
  const int qg = q0 + l16;                      // true q (may be >= S2_ for tail lanes)
  const int qload = (qg > S2_-1) ? (S2_-1) : qg;
  const size_t qkbase = ((size_t)b * S2_) * 512 + h * 64;
  const size_t vtbase = ((size_t)(b * 8 + h) * 64) * 1024;
  unsigned short* Pw = &Pl[w][0];

  // Q fragments (B-operand): B[k=d=half*32+quad*8+j][n=q=l16]
  bf16x8 qf[2];
  {
    const unsigned short* qp = Q + qkbase + (size_t)qload * 512 + quad * 8;
    qf[0] = *(const bf16x8*)(qp);
    qf[1] = *(const bf16x8*)(qp + 32);
  }

  float mi = -3e38f, li = 0.f;
  f32x4 ot[4];
  #pragma unroll
  for (int f = 0; f < 4; f++) ot[f] = f32x4{0.f,0.f,0.f,0.f};

  // key-tile range pruning (tile = 64 keys)
  int klo = 0, khi = S2_ - 1;
  if (q0wg + 63 < L2) {
    if (!backward) khi = q0wg + 63;
    else { klo = q0wg; khi = L2 - 1; }
  }

  for (int kt0 = klo; kt0 <= khi; kt0 += 64) {
    // --- load K fragments (A-operand): A[m=key=sub*16+l16][k=d]
    bf16x8 kf[4][2];
    #pragma unroll
    for (int sub = 0; sub < 4; sub++) {
      int kr = kt0 + sub*16 + l16; if (kr > S2_-1) kr = S2_-1;
      const unsigned short* kp = Kx + qkbase + (size_t)kr * 512 + quad * 8;
      kf[sub][0] = *(const bf16x8*)(kp);
      kf[sub][1] = *(const bf16x8*)(kp + 32);
    }
    // --- load VT fragments (A-operand for O^T): A[m=d=f*16+l16][k=key=g*32+quad*8+j]
    bf16x8 vf[4][2];
    #pragma unroll
    for (int f = 0; f < 4; f++) {
      const unsigned short* vp = VT + vtbase + (size_t)(f*16 + l16) * 1024 + kt0 + quad * 8;
      vf[f][0] = *(const bf16x8*)(vp);
      vf[f][1] = *(const bf16x8*)(vp + 32);
    }

    // --- S^T = K . Q^T : rows=keys, cols=q
    f32x4 st[4];
    #pragma unroll
    for (int sub = 0; sub < 4; sub++) {
      f32x4 s = f32x4{0.f,0.f,0.f,0.f};
      s = __builtin_amdgcn_mfma_f32_16x16x32_bf16(kf[sub][0], qf[0], s, 0, 0, 0);
      s = __builtin_amdgcn_mfma_f32_16x16x32_bf16(kf[sub][1], qf[1], s, 0, 0, 0);
      st[sub] = s;
    }

    // --- mask
    #pragma unroll
    for (int sub = 0; sub < 4; sub++) {
      #pragma unroll
      for (int r = 0; r < 4; r++) {
        int kg = kt0 + sub*16 + quad*4 + r;
        bool ok;
        if (!backward) ok = (kg < S2_) && ((qg >= L2) || (kg <= qg));
        else           ok = (kg < S2_) && ((qg >= L2) || ((kg >= qg) && (kg < L2)));
        if (!ok) st[sub][r] = -3e38f;
      }
    }

    // --- online softmax (per lane = one q column; keys spread over 16 regs x 4 quads)
    float mx = -3e38f;
    #pragma unroll
    for (int sub = 0; sub < 4; sub++)
      #pragma unroll
      for (int r = 0; r < 4; r++) mx = fmaxf(mx, st[sub][r]);
    mx = fmaxf(mx, __shfl_xor(mx, 16));
    mx = fmaxf(mx, __shfl_xor(mx, 32));
    float mn = fmaxf(mi, mx);
    float alpha = __expf(mi - mn);
    mi = mn;
    float rs = 0.f;
    #pragma unroll
    for (int sub = 0; sub < 4; sub++)
      #pragma unroll
      for (int r = 0; r < 4; r++) {
        float p = __expf(st[sub][r] - mn);
        st[sub][r] = p; rs += p;
      }
    rs += __shfl_xor(rs, 16);
    rs += __shfl_xor(rs, 32);
    li = li * alpha + rs;
    #pragma unroll
    for (int f = 0; f < 4; f++)
      #pragma unroll
      for (int r = 0; r < 4; r++) ot[f][r] *= alpha;

    // --- P to LDS (row q=l16, cols=keys), packed b64 writes; per-wave region, no barrier
    #pragma unroll
    for (int sub = 0; sub < 4; sub++) {
      ushort4 pk;
      pk.x = f2bf(st[sub][0]); pk.y = f2bf(st[sub][1]);
      pk.z = f2bf(st[sub][2]); pk.w = f2bf(st[sub][3]);
      *(ushort4*)&Pw[l16*PSTR + sub*16 + quad*4] = pk;
    }
    // --- P^T B-operand fragments: B[k=key=g*32+quad*8+j][n=q=l16]
    bf16x8 pfr0 = *(const bf16x8*)&Pw[l16*PSTR +      quad*8];
    bf16x8 pfr1 = *(const bf16x8*)&Pw[l16*PSTR + 32 + quad*8];

    // --- O^T += V^T . P^T
    #pragma unroll
    for (int f = 0; f < 4; f++) {
      ot[f] = __builtin_amdgcn_mfma_f32_16x16x32_bf16(vf[f][0], pfr0, ot[f], 0, 0, 0);
      ot[f] = __builtin_amdgcn_mfma_f32_16x16x32_bf16(vf[f][1], pfr1, ot[f], 0, 0, 0);
    }
  }

  // --- epilogue: O[q][d] = O^T/li ; value at (d=f*16+quad*4+r, q=l16)
  if (qg < S2_) {
    float rcp = 1.f / li;
    #pragma unroll
    for (int f = 0; f < 4; f++) {
      ushort4 pk;
      pk.x = f2bf(ot[f][0] * rcp); pk.y = f2bf(ot[f][1] * rcp);
      pk.z = f2bf(ot[f][2] * rcp); pk.w = f2bf(ot[f][3] * rcp);
      *(ushort4*)&CTX[qkbase + (size_t)qg * 512 + f*16 + quad*4] = pk;
    }
  }
}

// ----------------------------------------------------------------
extern "C" void kernel_launch(void* const* d_in, const int* in_sizes, int n_in,
                              void* d_out, int out_size, void* d_ws, size_t ws_size,
                              hipStream_t stream)
{
  const float* hidden = (const float*)d_in[0];
  const int*   lens   = (const int*)d_in[1];
  const float* fw[14]; for (int i = 0; i < 14; i++) fw[i] = (const float*)d_in[2 + i];
  const float* bw[14]; for (int i = 0; i < 14; i++) bw[i] = (const float*)d_in[16 + i];
  const float* attn_g = (const float*)d_in[30];
  const float* attn_b = (const float*)d_in[31];
  const float* o_w1 = (const float*)d_in[32];
  const float* o_b1 = (const float*)d_in[33];
  const float* o_w2 = (const float*)d_in[34];
  const float* o_b2 = (const float*)d_in[35];
  const float* o_lng = (const float*)d_in[36];
  const float* o_lnb = (const float*)d_in[37];

  char* ws = (char*)d_ws;
  size_t off = 0;
  auto alloc = [&](size_t bytes)->char* {
    off = (off + 255) & ~(size_t)255;
    char* p = ws + off; off += bytes; return p;
  };

  unsigned short* fw1t = (unsigned short*)alloc((size_t)1024*1024*2);
  unsigned short* fw2t = (unsigned short*)alloc((size_t)512*1024*2);
  unsigned short* fqt  = (unsigned short*)alloc((size_t)512*512*2);
  unsigned short* fkt  = (unsigned short*)alloc((size_t)512*512*2);
  unsigned short* fvt  = (unsigned short*)alloc((size_t)512*512*2);
  unsigned short* fot  = (unsigned short*)alloc((size_t)512*512*2);
  unsigned short* bw1t = (unsigned short*)alloc((size_t)1024*1024*2);
  unsigned short* bw2t = (unsigned short*)alloc((size_t)512*1024*2);
  unsigned short* bqt  = (unsigned short*)alloc((size_t)512*512*2);
  unsigned short* bkt  = (unsigned short*)alloc((size_t)512*512*2);
  unsigned short* bvt  = (unsigned short*)alloc((size_t)512*512*2);
  unsigned short* bot  = (unsigned short*)alloc((size_t)512*512*2);
  unsigned short* ow1t = (unsigned short*)alloc((size_t)1024*1024*2);
  unsigned short* ow2t = (unsigned short*)alloc((size_t)1024*1024*2);

  unsigned short* Xb = (unsigned short*)alloc((size_t)M_*1024*2); // also attn-LN output later
  unsigned short* H1 = (unsigned short*)alloc((size_t)M_*1024*2);
  float*          T1 = (float*)alloc((size_t)M_*512*4);
  unsigned short* LQ = (unsigned short*)alloc((size_t)M_*512*2);
  unsigned short* Qb = (unsigned short*)alloc((size_t)M_*512*2);
  unsigned short* Kb = (unsigned short*)alloc((size_t)M_*512*2);
  unsigned short* Vb = (unsigned short*)alloc((size_t)M_*512*2);
  unsigned short* CT = (unsigned short*)alloc((size_t)M_*512*2);
  float*          PF = (float*)alloc((size_t)M_*512*4);
  float*          PB = (float*)alloc((size_t)M_*512*4);
  // VT[b][h][d][s(pad 1024)] aliases T1 (free between LN and the next FFN2):
  // 8*8*64 rows * 1024 shorts * 2 B = 8.39 MB < 16.7 MB.
  unsigned short* VTb = (unsigned short*)T1;

  auto G = [&](const unsigned short* A, int lda, const unsigned short* Bt,
               const float* bias, void* C, int ldc, int N, int K, int mode){
    lma_gemm_bt<<<dim3(N/128, (M_ + 127)/128), 256, 0, stream>>>(A, lda, Bt, bias, C, ldc, M_, N, K, mode);
  };

  lma_prep_x<<<M_, 256, 0, stream>>>(hidden, Xb);

  // single batched launch for all 14 weight transposes
  {
    TPack tp;
    const float* srcs[14] = { fw[0], fw[2], fw[6], fw[8], fw[10], fw[12],
                              bw[0], bw[2], bw[6], bw[8], bw[10], bw[12],
                              o_w1, o_w2 };
    unsigned short* dsts[14] = { fw1t, fw2t, fqt, fkt, fvt, fot,
                                 bw1t, bw2t, bqt, bkt, bvt, bot,
                                 ow1t, ow2t };
    int Ks[14] = {1024,1024,512,512,512,512, 1024,1024,512,512,512,512, 1024,1024};
    int Ns[14] = {1024, 512,512,512,512,512, 1024, 512,512,512,512,512, 1024,1024};
    for (int i = 0; i < 14; i++){ tp.src[i]=srcs[i]; tp.dst[i]=dsts[i]; tp.K[i]=Ks[i]; tp.N[i]=Ns[i]; }
    lma_transpose_all<<<dim3(32, 32, 14), 256, 0, stream>>>(tp);
  }

  // ---- forward branch
  G(Xb, 1024, fw1t, fw[1], H1, 1024, 1024, 1024, 2);          // gelu FFN1 -> bf16
  G(H1, 1024, fw2t, fw[3], T1, 512, 512, 1024, 3);            // FFN2 -> f32
  lma_ln<<<M_, 256, 0, stream>>>(T1, fw[4], fw[5], 512, LQ, nullptr);
  G(LQ, 512, fqt, fw[7], Qb, 512, 512, 512, 1);               // Q (scaled 1/8)
  G(Xb, 1024, fkt, fw[9], Kb, 512, 512, 512, 0);              // K from f kv
  G(Xb, 1024, fvt, fw[11], Vb, 512, 512, 512, 0);             // V
  lma_vt<<<dim3(32, 16, 8), 256, 0, stream>>>(Vb, VTb);
  lma_attn2<<<dim3(16, 8, 8), 256, 0, stream>>>(Qb, Kb, VTb, CT, lens, 0);
  G(CT, 512, fot, fw[13], PF, 512, 512, 512, 3);              // out proj -> f32

  // ---- backward branch
  G(Xb, 1024, bw1t, bw[1], H1, 1024, 1024, 1024, 2);
  G(H1, 1024, bw2t, bw[3], T1, 512, 512, 1024, 3);            // overwrites VT (forward attn done)
  lma_ln<<<M_, 256, 0, stream>>>(T1, bw[4], bw[5], 512, LQ, nullptr);
  G(LQ, 512, bqt, bw[7], Qb, 512, 512, 512, 1);
  G(Xb + 512, 1024, bkt, bw[9], Kb, 512, 512, 512, 0);        // K from b kv (second half cols)
  G(Xb + 512, 1024, bvt, bw[11], Vb, 512, 512, 512, 0);
  lma_vt<<<dim3(32, 16, 8), 256, 0, stream>>>(Vb, VTb);
  lma_attn2<<<dim3(16, 8, 8), 256, 0, stream>>>(Qb, Kb, VTb, CT, lens, 1);
  G(CT, 512, bot, bw[13], PB, 512, 512, 512, 3);

  // ---- residual + attn LN (writes into Xb region as bf16)
  lma_attn_ln<<<M_, 256, 0, stream>>>(PF, PB, hidden, attn_g, attn_b, Xb);

  // ---- output FFN + final LN (GEMM stores remapped (s*B+b) rows straight into d_out; LN in place)
  G(Xb, 1024, ow1t, o_b1, H1, 1024, 1024, 1024, 2);
  G(H1, 1024, ow2t, o_b2, (float*)d_out, 1024, 1024, 1024, 4);
  lma_ln<<<M_, 256, 0, stream>>>((float*)d_out, o_lng, o_lnb, 1024, nullptr, (float*)d_out);
}

// Round 5
// 949.438 us; speedup vs baseline: 1.0449x; 1.0068x over previous
//
#include <hip/hip_runtime.h>
#include <cmath>

#define S_ 1024
#define B_ 8
#define H_ 512
#define S2_ 1022
#define M_ (B_*S2_)   // 8176

typedef __attribute__((ext_vector_type(8))) short bf16x8;
typedef __attribute__((ext_vector_type(4))) float f32x4;
typedef __attribute__((ext_vector_type(4))) unsigned int u32x4;
typedef __attribute__((ext_vector_type(2))) unsigned int u32x2;

__device__ __forceinline__ unsigned short f2bf(float f){
  unsigned int u = __float_as_uint(f);
  return (unsigned short)((u + 0x7fffu + ((u>>16)&1u)) >> 16);
}

__device__ __forceinline__ void glds16(const void* g, void* l){
  __builtin_amdgcn_global_load_lds((const __attribute__((address_space(1))) unsigned int*)g,
                                   (__attribute__((address_space(3))) unsigned int*)l, 16, 0, 0);
}

// ---------------------------------------------------------------- prep: build X = [f[:-2], bk[2:]] as bf16 (M x 1024)
__global__ __launch_bounds__(256) void lma_prep_x(const float* __restrict__ hidden,
                                                  unsigned short* __restrict__ Xb){
  int m = blockIdx.x; int dq = threadIdx.x * 4;
  int b = m / S2_, s = m - b * S2_;
  int srow = (dq < 512) ? s : (s + 2);
  const float* src = hidden + ((size_t)srow * B_ + b) * 1024 + dq;
  f32x4 v = *(const f32x4*)src;
  union { u32x2 u; unsigned short s4[4]; } pk;
  #pragma unroll
  for (int j = 0; j < 4; j++) pk.s4[j] = f2bf(v[j]);
  *(u32x2*)&Xb[(size_t)m * 1024 + dq] = pk.u;
}

// ---------------------------------------------------------------- batched weight transpose+cast: W(K x N) f32 -> WT(N x K) bf16
struct TPack {
  const float* src[14];
  unsigned short* dst[14];
  int K[14];
  int N[14];
};
__global__ __launch_bounds__(256) void lma_transpose_all(TPack p){
  int idx = blockIdx.z;
  int K = p.K[idx], N = p.N[idx];
  int kb = blockIdx.x * 32, nb = blockIdx.y * 32;
  if (kb >= K || nb >= N) return;
  const float* W = p.src[idx];
  unsigned short* WT = p.dst[idx];
  __shared__ float t[32][33];
  int tx = threadIdx.x & 31, ty = threadIdx.x >> 5;
  #pragma unroll
  for (int i = ty; i < 32; i += 8) t[i][tx] = W[(size_t)(kb + i) * N + nb + tx];
  __syncthreads();
  #pragma unroll
  for (int i = ty; i < 32; i += 8) WT[(size_t)(nb + i) * K + kb + tx] = f2bf(t[tx][i]);
}

// ---------------------------------------------------------------- V (M x 512 bf16) -> VT[b][h][d][s] (rows padded to 1024)
// Padding columns s in [S2_, 1024) are ZEROED — VT aliases a buffer whose
// stale fp32 halves can reinterpret as bf16 NaN; masked keys (p=0) would then
// poison the PV MFMA with 0*NaN. (Round 2/3 NaN root cause.)
__global__ __launch_bounds__(256) void lma_vt(const unsigned short* __restrict__ V,
                                              unsigned short* __restrict__ VT){
  __shared__ unsigned short t[32][34];
  int s0 = blockIdx.x * 32, c0 = blockIdx.y * 32, b = blockIdx.z;
  int tx = threadIdx.x & 31, ty = threadIdx.x >> 5;
  #pragma unroll
  for (int i = ty; i < 32; i += 8){
    int s = s0 + i; if (s > S2_-1) s = S2_-1;
    t[i][tx] = V[((size_t)b * S2_ + s) * 512 + c0 + tx];
  }
  __syncthreads();
  int s = s0 + tx;
  #pragma unroll
  for (int i = ty; i < 32; i += 8){
    int c = c0 + i, h = c >> 6, d = c & 63;
    VT[(((size_t)b * 8 + h) * 64 + d) * 1024 + s] = (s < S2_) ? t[tx][i] : (unsigned short)0;
  }
}

// ---------------------------------------------------------------- GEMM: C(MxN) = A(MxK,bf16,lda) * Bt(NxK,bf16)^T + bias
// modes: 0 bf16 bias | 1 bf16 (bias)*0.125 | 2 bf16 bias+gelu | 3 f32 bias | 4 f32 bias, row-remapped (s*B+b) store
__global__ __launch_bounds__(256) void lma_gemm_bt(
    const unsigned short* __restrict__ A, int lda,
    const unsigned short* __restrict__ Bt,
    const float* __restrict__ bias,
    void* __restrict__ Cout, int ldc,
    int M, int N, int K, int mode)
{
  __shared__ unsigned short Al[128*32];
  __shared__ unsigned short Bl[128*32];
  const int tid = threadIdx.x;
  const int w = tid >> 6, lane = tid & 63, quad = lane >> 4, l16 = lane & 15;
  const int m0 = blockIdx.y * 128, n0 = blockIdx.x * 128;
  const int wm = (w >> 1) * 64, wn = (w & 1) * 64;

  f32x4 acc[4][4];
  #pragma unroll
  for (int i = 0; i < 4; i++)
    #pragma unroll
    for (int f = 0; f < 4; f++) acc[i][f] = f32x4{0.f,0.f,0.f,0.f};

  const int srow = lane >> 2;        // 0..15
  const int spc  = (lane & 3) * 8;   // element offset in k

  for (int k0 = 0; k0 < K; k0 += 32) {
    #pragma unroll
    for (int c = 0; c < 2; c++) {
      int ra = w*32 + c*16 + srow;
      int ga = m0 + ra; if (ga > M-1) ga = M-1;
      glds16(A + (size_t)ga * lda + k0 + spc, &Al[(w*32 + c*16) * 32]);
      int gb = n0 + ra; if (gb > N-1) gb = N-1;
      glds16(Bt + (size_t)gb * K + k0 + spc, &Bl[(w*32 + c*16) * 32]);
    }
    __syncthreads();
    bf16x8 af[4], bfr[4];
    #pragma unroll
    for (int i = 0; i < 4; i++) af[i]  = *(const bf16x8*)&Al[(wm + i*16 + l16)*32 + quad*8];
    #pragma unroll
    for (int f = 0; f < 4; f++) bfr[f] = *(const bf16x8*)&Bl[(wn + f*16 + l16)*32 + quad*8];
    #pragma unroll
    for (int i = 0; i < 4; i++)
      #pragma unroll
      for (int f = 0; f < 4; f++)
        acc[i][f] = __builtin_amdgcn_mfma_f32_16x16x32_bf16(af[i], bfr[f], acc[i][f], 0, 0, 0);
    __syncthreads();
  }

  #pragma unroll
  for (int f = 0; f < 4; f++) {
    int col = n0 + wn + f*16 + l16;
    float bv = bias ? bias[col] : 0.f;
    #pragma unroll
    for (int i = 0; i < 4; i++) {
      #pragma unroll
      for (int r = 0; r < 4; r++) {
        int row = m0 + wm + i*16 + quad*4 + r;
        if (row < M) {
          float v = acc[i][f][r] + bv;
          if (mode == 2) v = 0.5f * v * (1.f + erff(v * 0.70710678118654752f));
          else if (mode == 1) v *= 0.125f;
          if (mode <= 2) ((unsigned short*)Cout)[(size_t)row * ldc + col] = f2bf(v);
          else if (mode == 3) ((float*)Cout)[(size_t)row * ldc + col] = v;
          else {
            int sr = row % S2_, br = row / S2_;
            ((float*)Cout)[((size_t)sr * B_ + br) * ldc + col] = v;
          }
        }
      }
    }
  }
}

// ---------------------------------------------------------------- block reduction helper (sum, sumsq) over 256 threads
__device__ __forceinline__ void lma_red2(float& s, float& sq){
  __shared__ float red[16];
  #pragma unroll
  for (int msk = 1; msk < 64; msk <<= 1){ s += __shfl_xor(s, msk); sq += __shfl_xor(sq, msk); }
  int w = threadIdx.x >> 6;
  if ((threadIdx.x & 63) == 0){ red[w] = s; red[8 + w] = sq; }
  __syncthreads();
  s  = red[0] + red[1] + red[2] + red[3];
  sq = red[8] + red[9] + red[10] + red[11];
}

// ---------------------------------------------------------------- LN: in f32 rows (M x D) -> bf16 out OR f32 out (in-place ok)
__global__ __launch_bounds__(256) void lma_ln(const float* __restrict__ in,
                                              const float* __restrict__ g, const float* __restrict__ bb,
                                              int D, unsigned short* __restrict__ obf, float* __restrict__ of32){
  int row = blockIdx.x, t = threadIdx.x;
  const float* x = in + (size_t)row * D;
  float s = 0.f, sq = 0.f;
  for (int d = t; d < D; d += 256){ float v = x[d]; s += v; sq += v * v; }
  lma_red2(s, sq);
  float mean = s / D;
  float var = sq / D - mean * mean;
  float rstd = rsqrtf(fmaxf(var, 0.f) + 1e-12f);
  if (obf) {
    for (int d = t; d < D; d += 256) {
      float v = (x[d] - mean) * rstd * g[d] + bb[d];
      obf[(size_t)row * D + d] = f2bf(v);
    }
  } else {
    for (int d = t; d < D; d += 256) {
      float v = (x[d] - mean) * rstd * g[d] + bb[d];
      of32[(size_t)row * D + d] = v;
    }
  }
}

// ---------------------------------------------------------------- attn LN: LN(residual(hidden) + [pf, pb]) -> bf16 (M x 1024)
__global__ __launch_bounds__(256) void lma_attn_ln(const float* __restrict__ pf, const float* __restrict__ pb,
                                                   const float* __restrict__ hidden,
                                                   const float* __restrict__ g, const float* __restrict__ bb,
                                                   unsigned short* __restrict__ out){
  int m = blockIdx.x, t = threadIdx.x;
  int b = m / S2_, s = m - b * S2_;
  const float* hf = hidden + ((size_t)s       * B_ + b) * 1024;
  const float* hb = hidden + ((size_t)(s + 2) * B_ + b) * 1024;
  float v[4]; float sum = 0.f, sq = 0.f;
  #pragma unroll
  for (int j = 0; j < 4; j++){
    int d = t + j * 256;
    float x = (d < 512) ? (pf[(size_t)m * 512 + d] + hf[d])
                        : (pb[(size_t)m * 512 + (d - 512)] + hb[d]);
    v[j] = x; sum += x; sq += x * x;
  }
  lma_red2(sum, sq);
  float mean = sum / 1024.f;
  float var = sq / 1024.f - mean * mean;
  float rstd = rsqrtf(fmaxf(var, 0.f) + 1e-12f);
  #pragma unroll
  for (int j = 0; j < 4; j++){
    int d = t + j * 256;
    float y = (v[j] - mean) * rstd * g[d] + bb[d];
    out[(size_t)m * 1024 + d] = f2bf(y);
  }
}

// ---------------------------------------------------------------- flash attention v3: S^T orientation, barrier-free,
// XCD-swizzled flat grid: block id = qt*64 + h*8 + b  =>  id%8 = b, so all
// 128 blocks of one batch land on one XCD (round-robin dispatch) and its
// Q+K+VT working set (3.2 MB) fits the 4 MB per-XCD L2.
// Wave-level k-range pruning (no barriers, waves independent).
#define PSTR 80
__global__ __launch_bounds__(256) void lma_attn2(const unsigned short* __restrict__ Q,
                                                 const unsigned short* __restrict__ Kx,
                                                 const unsigned short* __restrict__ VT,
                                                 unsigned short* __restrict__ CTX,
                                                 const int* __restrict__ lens, int backward){
  __shared__ __align__(16) unsigned short Pl[4][16*PSTR];

  const int tid = threadIdx.x;
  const int w = tid >> 6, lane = tid & 63, quad = lane >> 4, l16 = lane & 15;
  const int id = blockIdx.x;
  const int qt = id >> 6, h = (id >> 3) & 7, b = id & 7;
  const int L2 = lens[b] - 2;
  const int q0wg = qt * 64;
  const int q0 = q0wg + w * 16;
  const int qg = q0 + l16;                      // true q (may be >= S2_ for tail lanes)
  const int qload = (qg > S2_-1) ? (S2_-1) : qg;
  const size_t qkbase = ((size_t)b * S2_) * 512 + h * 64;
  const size_t vtbase = ((size_t)(b * 8 + h) * 64) * 1024;
  unsigned short* Pw = &Pl[w][0];

  // Q fragments (B-operand): B[k=d=half*32+quad*8+j][n=q=l16]
  bf16x8 qf[2];
  {
    const unsigned short* qp = Q + qkbase + (size_t)qload * 512 + quad * 8;
    qf[0] = *(const bf16x8*)(qp);
    qf[1] = *(const bf16x8*)(qp + 32);
  }

  float mi = -3e38f, li = 0.f;
  f32x4 ot[4];
  #pragma unroll
  for (int f = 0; f < 4; f++) ot[f] = f32x4{0.f,0.f,0.f,0.f};

  // wave-level key-tile range pruning (tile = 64 keys)
  int klo = 0, khi = S2_ - 1;
  if (q0 + 15 < L2) {                  // all 16 q-rows of this wave are causal rows
    if (!backward) khi = q0 + 15;
    else { klo = q0wg; khi = L2 - 1; }
  }

  for (int kt0 = klo; kt0 <= khi; kt0 += 64) {
    // --- load K fragments (A-operand): A[m=key=sub*16+l16][k=d]
    bf16x8 kf[4][2];
    #pragma unroll
    for (int sub = 0; sub < 4; sub++) {
      int kr = kt0 + sub*16 + l16; if (kr > S2_-1) kr = S2_-1;
      const unsigned short* kp = Kx + qkbase + (size_t)kr * 512 + quad * 8;
      kf[sub][0] = *(const bf16x8*)(kp);
      kf[sub][1] = *(const bf16x8*)(kp + 32);
    }
    // --- load VT fragments (A-operand for O^T): A[m=d=f*16+l16][k=key=g*32+quad*8+j]
    bf16x8 vf[4][2];
    #pragma unroll
    for (int f = 0; f < 4; f++) {
      const unsigned short* vp = VT + vtbase + (size_t)(f*16 + l16) * 1024 + kt0 + quad * 8;
      vf[f][0] = *(const bf16x8*)(vp);
      vf[f][1] = *(const bf16x8*)(vp + 32);
    }

    // --- S^T = K . Q^T : rows=keys, cols=q
    f32x4 st[4];
    #pragma unroll
    for (int sub = 0; sub < 4; sub++) {
      f32x4 s = f32x4{0.f,0.f,0.f,0.f};
      s = __builtin_amdgcn_mfma_f32_16x16x32_bf16(kf[sub][0], qf[0], s, 0, 0, 0);
      s = __builtin_amdgcn_mfma_f32_16x16x32_bf16(kf[sub][1], qf[1], s, 0, 0, 0);
      st[sub] = s;
    }

    // --- mask
    #pragma unroll
    for (int sub = 0; sub < 4; sub++) {
      #pragma unroll
      for (int r = 0; r < 4; r++) {
        int kg = kt0 + sub*16 + quad*4 + r;
        bool ok;
        if (!backward) ok = (kg < S2_) && ((qg >= L2) || (kg <= qg));
        else           ok = (kg < S2_) && ((qg >= L2) || ((kg >= qg) && (kg < L2)));
        if (!ok) st[sub][r] = -3e38f;
      }
    }

    // --- online softmax (per lane = one q column; keys spread over 16 regs x 4 quads)
    float mx = -3e38f;
    #pragma unroll
    for (int sub = 0; sub < 4; sub++)
      #pragma unroll
      for (int r = 0; r < 4; r++) mx = fmaxf(mx, st[sub][r]);
    mx = fmaxf(mx, __shfl_xor(mx, 16));
    mx = fmaxf(mx, __shfl_xor(mx, 32));
    float mn = fmaxf(mi, mx);
    float alpha = __expf(mi - mn);
    mi = mn;
    float rs = 0.f;
    #pragma unroll
    for (int sub = 0; sub < 4; sub++)
      #pragma unroll
      for (int r = 0; r < 4; r++) {
        float p = __expf(st[sub][r] - mn);
        st[sub][r] = p; rs += p;
      }
    rs += __shfl_xor(rs, 16);
    rs += __shfl_xor(rs, 32);
    li = li * alpha + rs;
    #pragma unroll
    for (int f = 0; f < 4; f++)
      #pragma unroll
      for (int r = 0; r < 4; r++) ot[f][r] *= alpha;

    // --- P to LDS (row q=l16, cols=keys), packed b64 writes; per-wave region, no barrier
    #pragma unroll
    for (int sub = 0; sub < 4; sub++) {
      ushort4 pk;
      pk.x = f2bf(st[sub][0]); pk.y = f2bf(st[sub][1]);
      pk.z = f2bf(st[sub][2]); pk.w = f2bf(st[sub][3]);
      *(ushort4*)&Pw[l16*PSTR + sub*16 + quad*4] = pk;
    }
    // --- P^T B-operand fragments: B[k=key=g*32+quad*8+j][n=q=l16]
    bf16x8 pfr0 = *(const bf16x8*)&Pw[l16*PSTR +      quad*8];
    bf16x8 pfr1 = *(const bf16x8*)&Pw[l16*PSTR + 32 + quad*8];

    // --- O^T += V^T . P^T
    #pragma unroll
    for (int f = 0; f < 4; f++) {
      ot[f] = __builtin_amdgcn_mfma_f32_16x16x32_bf16(vf[f][0], pfr0, ot[f], 0, 0, 0);
      ot[f] = __builtin_amdgcn_mfma_f32_16x16x32_bf16(vf[f][1], pfr1, ot[f], 0, 0, 0);
    }
  }

  // --- epilogue: O[q][d] = O^T/li ; value at (d=f*16+quad*4+r, q=l16)
  if (qg < S2_) {
    float rcp = 1.f / li;
    #pragma unroll
    for (int f = 0; f < 4; f++) {
      ushort4 pk;
      pk.x = f2bf(ot[f][0] * rcp); pk.y = f2bf(ot[f][1] * rcp);
      pk.z = f2bf(ot[f][2] * rcp); pk.w = f2bf(ot[f][3] * rcp);
      *(ushort4*)&CTX[qkbase + (size_t)qg * 512 + f*16 + quad*4] = pk;
    }
  }
}

// ----------------------------------------------------------------
extern "C" void kernel_launch(void* const* d_in, const int* in_sizes, int n_in,
                              void* d_out, int out_size, void* d_ws, size_t ws_size,
                              hipStream_t stream)
{
  const float* hidden = (const float*)d_in[0];
  const int*   lens   = (const int*)d_in[1];
  const float* fw[14]; for (int i = 0; i < 14; i++) fw[i] = (const float*)d_in[2 + i];
  const float* bw[14]; for (int i = 0; i < 14; i++) bw[i] = (const float*)d_in[16 + i];
  const float* attn_g = (const float*)d_in[30];
  const float* attn_b = (const float*)d_in[31];
  const float* o_w1 = (const float*)d_in[32];
  const float* o_b1 = (const float*)d_in[33];
  const float* o_w2 = (const float*)d_in[34];
  const float* o_b2 = (const float*)d_in[35];
  const float* o_lng = (const float*)d_in[36];
  const float* o_lnb = (const float*)d_in[37];

  char* ws = (char*)d_ws;
  size_t off = 0;
  auto alloc = [&](size_t bytes)->char* {
    off = (off + 255) & ~(size_t)255;
    char* p = ws + off; off += bytes; return p;
  };

  unsigned short* fw1t = (unsigned short*)alloc((size_t)1024*1024*2);
  unsigned short* fw2t = (unsigned short*)alloc((size_t)512*1024*2);
  unsigned short* fqt  = (unsigned short*)alloc((size_t)512*512*2);
  unsigned short* fkt  = (unsigned short*)alloc((size_t)512*512*2);
  unsigned short* fvt  = (unsigned short*)alloc((size_t)512*512*2);
  unsigned short* fot  = (unsigned short*)alloc((size_t)512*512*2);
  unsigned short* bw1t = (unsigned short*)alloc((size_t)1024*1024*2);
  unsigned short* bw2t = (unsigned short*)alloc((size_t)512*1024*2);
  unsigned short* bqt  = (unsigned short*)alloc((size_t)512*512*2);
  unsigned short* bkt  = (unsigned short*)alloc((size_t)512*512*2);
  unsigned short* bvt  = (unsigned short*)alloc((size_t)512*512*2);
  unsigned short* bot  = (unsigned short*)alloc((size_t)512*512*2);
  unsigned short* ow1t = (unsigned short*)alloc((size_t)1024*1024*2);
  unsigned short* ow2t = (unsigned short*)alloc((size_t)1024*1024*2);

  unsigned short* Xb = (unsigned short*)alloc((size_t)M_*1024*2); // also attn-LN output later
  unsigned short* H1 = (unsigned short*)alloc((size_t)M_*1024*2);
  float*          T1 = (float*)alloc((size_t)M_*512*4);
  unsigned short* LQ = (unsigned short*)alloc((size_t)M_*512*2);
  unsigned short* Qb = (unsigned short*)alloc((size_t)M_*512*2);
  unsigned short* Kb = (unsigned short*)alloc((size_t)M_*512*2);
  unsigned short* Vb = (unsigned short*)alloc((size_t)M_*512*2);
  unsigned short* CT = (unsigned short*)alloc((size_t)M_*512*2);
  float*          PF = (float*)alloc((size_t)M_*512*4);
  float*          PB = (float*)alloc((size_t)M_*512*4);
  // VT[b][h][d][s(pad 1024)] aliases T1 (free between LN and the next FFN2):
  // 8*8*64 rows * 1024 shorts * 2 B = 8.39 MB < 16.7 MB.
  unsigned short* VTb = (unsigned short*)T1;

  auto G = [&](const unsigned short* A, int lda, const unsigned short* Bt,
               const float* bias, void* C, int ldc, int N, int K, int mode){
    lma_gemm_bt<<<dim3(N/128, (M_ + 127)/128), 256, 0, stream>>>(A, lda, Bt, bias, C, ldc, M_, N, K, mode);
  };

  lma_prep_x<<<M_, 256, 0, stream>>>(hidden, Xb);

  // single batched launch for all 14 weight transposes
  {
    TPack tp;
    const float* srcs[14] = { fw[0], fw[2], fw[6], fw[8], fw[10], fw[12],
                              bw[0], bw[2], bw[6], bw[8], bw[10], bw[12],
                              o_w1, o_w2 };
    unsigned short* dsts[14] = { fw1t, fw2t, fqt, fkt, fvt, fot,
                                 bw1t, bw2t, bqt, bkt, bvt, bot,
                                 ow1t, ow2t };
    int Ks[14] = {1024,1024,512,512,512,512, 1024,1024,512,512,512,512, 1024,1024};
    int Ns[14] = {1024, 512,512,512,512,512, 1024, 512,512,512,512,512, 1024,1024};
    for (int i = 0; i < 14; i++){ tp.src[i]=srcs[i]; tp.dst[i]=dsts[i]; tp.K[i]=Ks[i]; tp.N[i]=Ns[i]; }
    lma_transpose_all<<<dim3(32, 32, 14), 256, 0, stream>>>(tp);
  }

  // ---- forward branch
  G(Xb, 1024, fw1t, fw[1], H1, 1024, 1024, 1024, 2);          // gelu FFN1 -> bf16
  G(H1, 1024, fw2t, fw[3], T1, 512, 512, 1024, 3);            // FFN2 -> f32
  lma_ln<<<M_, 256, 0, stream>>>(T1, fw[4], fw[5], 512, LQ, nullptr);
  G(LQ, 512, fqt, fw[7], Qb, 512, 512, 512, 1);               // Q (scaled 1/8)
  G(Xb, 1024, fkt, fw[9], Kb, 512, 512, 512, 0);              // K from f kv
  G(Xb, 1024, fvt, fw[11], Vb, 512, 512, 512, 0);             // V
  lma_vt<<<dim3(32, 16, 8), 256, 0, stream>>>(Vb, VTb);
  lma_attn2<<<dim3(1024), 256, 0, stream>>>(Qb, Kb, VTb, CT, lens, 0);
  G(CT, 512, fot, fw[13], PF, 512, 512, 512, 3);              // out proj -> f32

  // ---- backward branch
  G(Xb, 1024, bw1t, bw[1], H1, 1024, 1024, 1024, 2);
  G(H1, 1024, bw2t, bw[3], T1, 512, 512, 1024, 3);            // overwrites VT (forward attn done)
  lma_ln<<<M_, 256, 0, stream>>>(T1, bw[4], bw[5], 512, LQ, nullptr);
  G(LQ, 512, bqt, bw[7], Qb, 512, 512, 512, 1);
  G(Xb + 512, 1024, bkt, bw[9], Kb, 512, 512, 512, 0);        // K from b kv (second half cols)
  G(Xb + 512, 1024, bvt, bw[11], Vb, 512, 512, 512, 0);
  lma_vt<<<dim3(32, 16, 8), 256, 0, stream>>>(Vb, VTb);
  lma_attn2<<<dim3(1024), 256, 0, stream>>>(Qb, Kb, VTb, CT, lens, 1);
  G(CT, 512, bot, bw[13], PB, 512, 512, 512, 3);

  // ---- residual + attn LN (writes into Xb region as bf16)
  lma_attn_ln<<<M_, 256, 0, stream>>>(PF, PB, hidden, attn_g, attn_b, Xb);

  // ---- output FFN + final LN (GEMM stores remapped (s*B+b) rows straight into d_out; LN in place)
  G(Xb, 1024, ow1t, o_b1, H1, 1024, 1024, 1024, 2);
  G(H1, 1024, ow2t, o_b2, (float*)d_out, 1024, 1024, 1024, 4);
  lma_ln<<<M_, 256, 0, stream>>>((float*)d_out, o_lng, o_lnb, 1024, nullptr, (float*)d_out);
}

// Round 6
// 788.840 us; speedup vs baseline: 1.2577x; 1.2036x over previous
//
#include <hip/hip_runtime.h>
#include <cmath>

#define S_ 1024
#define B_ 8
#define H_ 512
#define S2_ 1022
#define M_ (B_*S2_)     // 8176
#define PAD_ 8192
#define VTS_ ((size_t)8*8*64*1024)   // VT per-branch stride (4194304 shorts)

typedef __attribute__((ext_vector_type(8))) short bf16x8;
typedef __attribute__((ext_vector_type(4))) float f32x4;
typedef __attribute__((ext_vector_type(4))) unsigned int u32x4;
typedef __attribute__((ext_vector_type(2))) unsigned int u32x2;

__device__ __forceinline__ unsigned short f2bf(float f){
  unsigned int u = __float_as_uint(f);
  return (unsigned short)((u + 0x7fffu + ((u>>16)&1u)) >> 16);
}

__device__ __forceinline__ void glds16(const void* g, void* l){
  __builtin_amdgcn_global_load_lds((const __attribute__((address_space(1))) unsigned int*)g,
                                   (__attribute__((address_space(3))) unsigned int*)l, 16, 0, 0);
}

// ---------------------------------------------------------------- prep: X = [f[:-2], bk[2:]] bf16 (M_ x 1024)
__global__ __launch_bounds__(256) void lma_prep_x(const float* __restrict__ hidden,
                                                  unsigned short* __restrict__ Xb){
  int m = blockIdx.x; int dq = threadIdx.x * 4;
  int b = m / S2_, s = m - b * S2_;
  int srow = (dq < 512) ? s : (s + 2);
  const float* src = hidden + ((size_t)srow * B_ + b) * 1024 + dq;
  f32x4 v = *(const f32x4*)src;
  union { u32x2 u; unsigned short s4[4]; } pk;
  #pragma unroll
  for (int j = 0; j < 4; j++) pk.s4[j] = f2bf(v[j]);
  *(u32x2*)&Xb[(size_t)m * 1024 + dq] = pk.u;
}

// ---------------------------------------------------------------- batched weight transpose+cast
struct TPack {
  const float* src[14];
  unsigned short* dst[14];
  int K[14];
  int N[14];
};
__global__ __launch_bounds__(256) void lma_transpose_all(TPack p){
  int idx = blockIdx.z;
  int K = p.K[idx], N = p.N[idx];
  int kb = blockIdx.x * 32, nb = blockIdx.y * 32;
  if (kb >= K || nb >= N) return;
  const float* W = p.src[idx];
  unsigned short* WT = p.dst[idx];
  __shared__ float t[32][33];
  int tx = threadIdx.x & 31, ty = threadIdx.x >> 5;
  #pragma unroll
  for (int i = ty; i < 32; i += 8) t[i][tx] = W[(size_t)(kb + i) * N + nb + tx];
  __syncthreads();
  #pragma unroll
  for (int i = ty; i < 32; i += 8) WT[(size_t)(nb + i) * K + kb + tx] = f2bf(t[tx][i]);
}

// ---------------------------------------------------------------- concat K/V biases: out[0..1023]=f(k|v), [1024..2047]=b(k|v)
__global__ __launch_bounds__(256) void lma_biascat(const float* __restrict__ fk, const float* __restrict__ fv,
                                                   const float* __restrict__ bk, const float* __restrict__ bv,
                                                   float* __restrict__ out){
  int i = blockIdx.x * 256 + threadIdx.x;     // 0..2047
  int fb = i >> 10, col = i & 1023;
  const float* s = (col < 512) ? (fb ? bk : fk) : (fb ? bv : fv);
  out[i] = s[col & 511];
}

// ---------------------------------------------------------------- V (in KV2, cols 512..1023) -> VT2[fb][b][h][d][s pad 1024]
// Pad cols s in [S2_,1024) ZEROED (aliased buffer may hold bf16-NaN bit patterns).
__global__ __launch_bounds__(256) void lma_vt2(const unsigned short* __restrict__ KV2,
                                               unsigned short* __restrict__ VT2){
  __shared__ unsigned short t[32][34];
  int s0 = blockIdx.x * 32, c0 = blockIdx.y * 32;
  int z = blockIdx.z, fb = z >> 3, b = z & 7;
  const unsigned short* V = KV2 + (size_t)fb * PAD_ * 1024 + 512;
  unsigned short* VT = VT2 + (size_t)fb * VTS_;
  int tx = threadIdx.x & 31, ty = threadIdx.x >> 5;
  #pragma unroll
  for (int i = ty; i < 32; i += 8){
    int s = s0 + i; if (s > S2_-1) s = S2_-1;
    t[i][tx] = V[((size_t)b * S2_ + s) * 1024 + c0 + tx];
  }
  __syncthreads();
  int s = s0 + tx;
  #pragma unroll
  for (int i = ty; i < 32; i += 8){
    int c = c0 + i, h = c >> 6, d = c & 63;
    VT[(((size_t)b * 8 + h) * 64 + d) * 1024 + s] = (s < S2_) ? t[tx][i] : (unsigned short)0;
  }
}

// ---------------------------------------------------------------- branch-combined GEMM
// C(MxN) = A * Bt^T + bias; rows < 8192 use (Bt0,bias0), rows >= 8192 use (Bt1,bias1).
// amap: 0 = A row direct (clamped to M-1); 1 = A row = (r&8191) clamped to M_-1;
//       2 = like 1 plus +512 column offset for branch 1 (fused KV from X halves).
// modes: 0 bf16 bias | 1 bf16 bias*0.125 | 2 bf16 bias+gelu | 3 f32 bias | 4 f32 bias row-remap (s*B+b), M==M_ only
__global__ __launch_bounds__(256) void lma_gemm2(
    const unsigned short* __restrict__ A, int lda,
    const unsigned short* __restrict__ Bt0, const unsigned short* __restrict__ Bt1,
    const float* __restrict__ bias0, const float* __restrict__ bias1,
    void* __restrict__ Cout, int ldc,
    int M, int N, int K, int mode, int amap)
{
  __shared__ unsigned short Al[128*32];
  __shared__ unsigned short Bl[128*32];
  const int tid = threadIdx.x;
  const int w = tid >> 6, lane = tid & 63, quad = lane >> 4, l16 = lane & 15;
  const int m0 = blockIdx.y * 128, n0 = blockIdx.x * 128;
  const int brch = m0 >> 13;                       // 0 or 1, never straddles (8192%128==0)
  const unsigned short* Bt = brch ? Bt1 : Bt0;
  const float* bias = brch ? bias1 : bias0;
  const int coloff = (amap == 2 && brch) ? 512 : 0;
  const int wm = (w >> 1) * 64, wn = (w & 1) * 64;

  f32x4 acc[4][4];
  #pragma unroll
  for (int i = 0; i < 4; i++)
    #pragma unroll
    for (int f = 0; f < 4; f++) acc[i][f] = f32x4{0.f,0.f,0.f,0.f};

  const int srow = lane >> 2;
  const int spc  = (lane & 3) * 8;

  for (int k0 = 0; k0 < K; k0 += 32) {
    #pragma unroll
    for (int c = 0; c < 2; c++) {
      int ra = w*32 + c*16 + srow;
      int ga = m0 + ra;
      int ar;
      if (amap == 0) { ar = (ga > M-1) ? (M-1) : ga; }
      else { ar = ga & (PAD_-1); if (ar > M_-1) ar = M_-1; }
      glds16(A + (size_t)ar * lda + coloff + k0 + spc, &Al[(w*32 + c*16) * 32]);
      int gb = n0 + ra; if (gb > N-1) gb = N-1;
      glds16(Bt + (size_t)gb * K + k0 + spc, &Bl[(w*32 + c*16) * 32]);
    }
    __syncthreads();
    bf16x8 af[4], bfr[4];
    #pragma unroll
    for (int i = 0; i < 4; i++) af[i]  = *(const bf16x8*)&Al[(wm + i*16 + l16)*32 + quad*8];
    #pragma unroll
    for (int f = 0; f < 4; f++) bfr[f] = *(const bf16x8*)&Bl[(wn + f*16 + l16)*32 + quad*8];
    #pragma unroll
    for (int i = 0; i < 4; i++)
      #pragma unroll
      for (int f = 0; f < 4; f++)
        acc[i][f] = __builtin_amdgcn_mfma_f32_16x16x32_bf16(af[i], bfr[f], acc[i][f], 0, 0, 0);
    __syncthreads();
  }

  #pragma unroll
  for (int f = 0; f < 4; f++) {
    int col = n0 + wn + f*16 + l16;
    float bv = bias ? bias[col] : 0.f;
    #pragma unroll
    for (int i = 0; i < 4; i++) {
      #pragma unroll
      for (int r = 0; r < 4; r++) {
        int row = m0 + wm + i*16 + quad*4 + r;
        if (row < M) {
          float v = acc[i][f][r] + bv;
          if (mode == 2) v = 0.5f * v * (1.f + erff(v * 0.70710678118654752f));
          else if (mode == 1) v *= 0.125f;
          if (mode <= 2) ((unsigned short*)Cout)[(size_t)row * ldc + col] = f2bf(v);
          else if (mode == 3) ((float*)Cout)[(size_t)row * ldc + col] = v;
          else {
            int sr = row % S2_, bb2 = row / S2_;
            ((float*)Cout)[((size_t)sr * B_ + bb2) * ldc + col] = v;
          }
        }
      }
    }
  }
}

// ---------------------------------------------------------------- block reduction helper
__device__ __forceinline__ void lma_red2(float& s, float& sq){
  __shared__ float red[16];
  #pragma unroll
  for (int msk = 1; msk < 64; msk <<= 1){ s += __shfl_xor(s, msk); sq += __shfl_xor(sq, msk); }
  int w = threadIdx.x >> 6;
  if ((threadIdx.x & 63) == 0){ red[w] = s; red[8 + w] = sq; }
  __syncthreads();
  s  = red[0] + red[1] + red[2] + red[3];
  sq = red[8] + red[9] + red[10] + red[11];
}

// ---------------------------------------------------------------- generic LN (f32 in, bf16 or f32 out)
__global__ __launch_bounds__(256) void lma_ln(const float* __restrict__ in,
                                              const float* __restrict__ g, const float* __restrict__ bb,
                                              int D, unsigned short* __restrict__ obf, float* __restrict__ of32){
  int row = blockIdx.x, t = threadIdx.x;
  const float* x = in + (size_t)row * D;
  float s = 0.f, sq = 0.f;
  for (int d = t; d < D; d += 256){ float v = x[d]; s += v; sq += v * v; }
  lma_red2(s, sq);
  float mean = s / D;
  float var = sq / D - mean * mean;
  float rstd = rsqrtf(fmaxf(var, 0.f) + 1e-12f);
  if (obf) {
    for (int d = t; d < D; d += 256) obf[(size_t)row * D + d] = f2bf((x[d] - mean) * rstd * g[d] + bb[d]);
  } else {
    for (int d = t; d < D; d += 256) of32[(size_t)row * D + d] = (x[d] - mean) * rstd * g[d] + bb[d];
  }
}

// ---------------------------------------------------------------- branch-combined LN over T12 (D=512) -> LQ2 bf16
__global__ __launch_bounds__(256) void lma_ln2(const float* __restrict__ T12,
                                               const float* __restrict__ fg, const float* __restrict__ fbb,
                                               const float* __restrict__ bg, const float* __restrict__ bbb,
                                               unsigned short* __restrict__ LQ2){
  int m = blockIdx.x, t = threadIdx.x;           // 0..2*M_-1
  int fb = (m >= M_);
  int idx = m - fb * M_;
  const float* g = fb ? bg : fg;
  const float* bb = fb ? bbb : fbb;
  const float* x = T12 + ((size_t)fb * PAD_ + idx) * 512;
  unsigned short* o = LQ2 + ((size_t)fb * PAD_ + idx) * 512;
  float v0 = x[t], v1 = x[t + 256];
  float s = v0 + v1, sq = v0*v0 + v1*v1;
  lma_red2(s, sq);
  float mean = s / 512.f;
  float var = sq / 512.f - mean * mean;
  float rstd = rsqrtf(fmaxf(var, 0.f) + 1e-12f);
  o[t]       = f2bf((v0 - mean) * rstd * g[t]       + bb[t]);
  o[t + 256] = f2bf((v1 - mean) * rstd * g[t + 256] + bb[t + 256]);
}

// ---------------------------------------------------------------- attn LN: LN(residual(hidden)+[pf,pb]) -> bf16 (M_ x 1024)
__global__ __launch_bounds__(256) void lma_attn_ln(const float* __restrict__ pf, const float* __restrict__ pb,
                                                   const float* __restrict__ hidden,
                                                   const float* __restrict__ g, const float* __restrict__ bb,
                                                   unsigned short* __restrict__ out){
  int m = blockIdx.x, t = threadIdx.x;
  int b = m / S2_, s = m - b * S2_;
  const float* hf = hidden + ((size_t)s       * B_ + b) * 1024;
  const float* hb = hidden + ((size_t)(s + 2) * B_ + b) * 1024;
  float v[4]; float sum = 0.f, sq = 0.f;
  #pragma unroll
  for (int j = 0; j < 4; j++){
    int d = t + j * 256;
    float x = (d < 512) ? (pf[(size_t)m * 512 + d] + hf[d])
                        : (pb[(size_t)m * 512 + (d - 512)] + hb[d]);
    v[j] = x; sum += x; sq += x * x;
  }
  lma_red2(sum, sq);
  float mean = sum / 1024.f;
  float var = sq / 1024.f - mean * mean;
  float rstd = rsqrtf(fmaxf(var, 0.f) + 1e-12f);
  #pragma unroll
  for (int j = 0; j < 4; j++){
    int d = t + j * 256;
    out[(size_t)m * 1024 + d] = f2bf((v[j] - mean) * rstd * g[d] + bb[d]);
  }
}

// ---------------------------------------------------------------- combined flash attention (f+b in ONE launch, 2048 blocks)
// id = fb*1024 + qt*64 + h*8 + b  =>  id%8 = b (XCD locality), fb = forward/backward.
// Barrier-free, S^T orientation, wave-level k pruning.
#define PSTR 80
__global__ __launch_bounds__(256) void lma_attn3(const unsigned short* __restrict__ Q2,
                                                 const unsigned short* __restrict__ KV2,
                                                 const unsigned short* __restrict__ VT2,
                                                 unsigned short* __restrict__ CT2,
                                                 const int* __restrict__ lens){
  __shared__ __align__(16) unsigned short Pl[4][16*PSTR];

  const int tid = threadIdx.x;
  const int w = tid >> 6, lane = tid & 63, quad = lane >> 4, l16 = lane & 15;
  const int id = blockIdx.x;
  const int fb = id >> 10, rid = id & 1023;
  const int qt = rid >> 6, h = (rid >> 3) & 7, b = rid & 7;
  const int backward = fb;
  const int L2 = lens[b] - 2;
  const int q0wg = qt * 64;
  const int q0 = q0wg + w * 16;
  const int qg = q0 + l16;
  const int qload = (qg > S2_-1) ? (S2_-1) : qg;

  const unsigned short* Q  = Q2  + (size_t)fb * PAD_ * 512;
  const unsigned short* Kx = KV2 + (size_t)fb * PAD_ * 1024;
  const unsigned short* VT = VT2 + (size_t)fb * VTS_;
  unsigned short* CTX      = CT2 + (size_t)fb * PAD_ * 512;
  const size_t qbase  = ((size_t)b * S2_) * 512  + h * 64;   // Q/CT rows, stride 512
  const size_t kbase  = ((size_t)b * S2_) * 1024 + h * 64;   // K rows inside KV2, stride 1024
  const size_t vtbase = ((size_t)(b * 8 + h) * 64) * 1024;
  unsigned short* Pw = &Pl[w][0];

  bf16x8 qf[2];
  {
    const unsigned short* qp = Q + qbase + (size_t)qload * 512 + quad * 8;
    qf[0] = *(const bf16x8*)(qp);
    qf[1] = *(const bf16x8*)(qp + 32);
  }

  float mi = -3e38f, li = 0.f;
  f32x4 ot[4];
  #pragma unroll
  for (int f = 0; f < 4; f++) ot[f] = f32x4{0.f,0.f,0.f,0.f};

  int klo = 0, khi = S2_ - 1;
  if (q0 + 15 < L2) {
    if (!backward) khi = q0 + 15;
    else { klo = q0wg; khi = L2 - 1; }
  }

  for (int kt0 = klo; kt0 <= khi; kt0 += 64) {
    bf16x8 kf[4][2];
    #pragma unroll
    for (int sub = 0; sub < 4; sub++) {
      int kr = kt0 + sub*16 + l16; if (kr > S2_-1) kr = S2_-1;
      const unsigned short* kp = Kx + kbase + (size_t)kr * 1024 + quad * 8;
      kf[sub][0] = *(const bf16x8*)(kp);
      kf[sub][1] = *(const bf16x8*)(kp + 32);
    }
    bf16x8 vf[4][2];
    #pragma unroll
    for (int f = 0; f < 4; f++) {
      const unsigned short* vp = VT + vtbase + (size_t)(f*16 + l16) * 1024 + kt0 + quad * 8;
      vf[f][0] = *(const bf16x8*)(vp);
      vf[f][1] = *(const bf16x8*)(vp + 32);
    }

    f32x4 st[4];
    #pragma unroll
    for (int sub = 0; sub < 4; sub++) {
      f32x4 s = f32x4{0.f,0.f,0.f,0.f};
      s = __builtin_amdgcn_mfma_f32_16x16x32_bf16(kf[sub][0], qf[0], s, 0, 0, 0);
      s = __builtin_amdgcn_mfma_f32_16x16x32_bf16(kf[sub][1], qf[1], s, 0, 0, 0);
      st[sub] = s;
    }

    #pragma unroll
    for (int sub = 0; sub < 4; sub++) {
      #pragma unroll
      for (int r = 0; r < 4; r++) {
        int kg = kt0 + sub*16 + quad*4 + r;
        bool ok;
        if (!backward) ok = (kg < S2_) && ((qg >= L2) || (kg <= qg));
        else           ok = (kg < S2_) && ((qg >= L2) || ((kg >= qg) && (kg < L2)));
        if (!ok) st[sub][r] = -3e38f;
      }
    }

    float mx = -3e38f;
    #pragma unroll
    for (int sub = 0; sub < 4; sub++)
      #pragma unroll
      for (int r = 0; r < 4; r++) mx = fmaxf(mx, st[sub][r]);
    mx = fmaxf(mx, __shfl_xor(mx, 16));
    mx = fmaxf(mx, __shfl_xor(mx, 32));
    float mn = fmaxf(mi, mx);
    float alpha = __expf(mi - mn);
    mi = mn;
    float rs = 0.f;
    #pragma unroll
    for (int sub = 0; sub < 4; sub++)
      #pragma unroll
      for (int r = 0; r < 4; r++) {
        float p = __expf(st[sub][r] - mn);
        st[sub][r] = p; rs += p;
      }
    rs += __shfl_xor(rs, 16);
    rs += __shfl_xor(rs, 32);
    li = li * alpha + rs;
    #pragma unroll
    for (int f = 0; f < 4; f++)
      #pragma unroll
      for (int r = 0; r < 4; r++) ot[f][r] *= alpha;

    #pragma unroll
    for (int sub = 0; sub < 4; sub++) {
      ushort4 pk;
      pk.x = f2bf(st[sub][0]); pk.y = f2bf(st[sub][1]);
      pk.z = f2bf(st[sub][2]); pk.w = f2bf(st[sub][3]);
      *(ushort4*)&Pw[l16*PSTR + sub*16 + quad*4] = pk;
    }
    bf16x8 pfr0 = *(const bf16x8*)&Pw[l16*PSTR +      quad*8];
    bf16x8 pfr1 = *(const bf16x8*)&Pw[l16*PSTR + 32 + quad*8];

    #pragma unroll
    for (int f = 0; f < 4; f++) {
      ot[f] = __builtin_amdgcn_mfma_f32_16x16x32_bf16(vf[f][0], pfr0, ot[f], 0, 0, 0);
      ot[f] = __builtin_amdgcn_mfma_f32_16x16x32_bf16(vf[f][1], pfr1, ot[f], 0, 0, 0);
    }
  }

  if (qg < S2_) {
    float rcp = 1.f / li;
    #pragma unroll
    for (int f = 0; f < 4; f++) {
      ushort4 pk;
      pk.x = f2bf(ot[f][0] * rcp); pk.y = f2bf(ot[f][1] * rcp);
      pk.z = f2bf(ot[f][2] * rcp); pk.w = f2bf(ot[f][3] * rcp);
      *(ushort4*)&CTX[qbase + (size_t)qg * 512 + f*16 + quad*4] = pk;
    }
  }
}

// ----------------------------------------------------------------
extern "C" void kernel_launch(void* const* d_in, const int* in_sizes, int n_in,
                              void* d_out, int out_size, void* d_ws, size_t ws_size,
                              hipStream_t stream)
{
  const float* hidden = (const float*)d_in[0];
  const int*   lens   = (const int*)d_in[1];
  const float* fw[14]; for (int i = 0; i < 14; i++) fw[i] = (const float*)d_in[2 + i];
  const float* bw[14]; for (int i = 0; i < 14; i++) bw[i] = (const float*)d_in[16 + i];
  const float* attn_g = (const float*)d_in[30];
  const float* attn_b = (const float*)d_in[31];
  const float* o_w1 = (const float*)d_in[32];
  const float* o_b1 = (const float*)d_in[33];
  const float* o_w2 = (const float*)d_in[34];
  const float* o_b2 = (const float*)d_in[35];
  const float* o_lng = (const float*)d_in[36];
  const float* o_lnb = (const float*)d_in[37];
  // branch map: 0 w1,1 b1,2 w2,3 b2,4 lng,5 lnb,6 qw,7 qb,8 kw,9 kb,10 vw,11 vb,12 ow,13 ob

  char* ws = (char*)d_ws;
  size_t off = 0;
  auto alloc = [&](size_t bytes)->char* {
    off = (off + 255) & ~(size_t)255;
    char* p = ws + off; off += bytes; return p;
  };

  unsigned short* fw1t = (unsigned short*)alloc((size_t)1024*1024*2);
  unsigned short* fw2t = (unsigned short*)alloc((size_t)512*1024*2);
  unsigned short* fqt  = (unsigned short*)alloc((size_t)512*512*2);
  unsigned short* fkvt = (unsigned short*)alloc((size_t)1024*512*2);  // [K(512 rows); V(512 rows)]
  unsigned short* fot  = (unsigned short*)alloc((size_t)512*512*2);
  unsigned short* bw1t = (unsigned short*)alloc((size_t)1024*1024*2);
  unsigned short* bw2t = (unsigned short*)alloc((size_t)512*1024*2);
  unsigned short* bqt  = (unsigned short*)alloc((size_t)512*512*2);
  unsigned short* bkvt = (unsigned short*)alloc((size_t)1024*512*2);
  unsigned short* bot  = (unsigned short*)alloc((size_t)512*512*2);
  unsigned short* ow1t = (unsigned short*)alloc((size_t)1024*1024*2);
  unsigned short* ow2t = (unsigned short*)alloc((size_t)1024*1024*2);
  float*          biasKV = (float*)alloc(2048*4);

  unsigned short* Xb   = (unsigned short*)alloc((size_t)M_*1024*2);
  // big1: H12 (FFN1 out) -> KV2 (K|V proj) -> H1out (out-FFN1)
  unsigned short* big1 = (unsigned short*)alloc((size_t)2*PAD_*1024*2);
  // big2: T12 (FFN2 f32) -> VT2 (bf16, 16.8MB of 33.6) -> P2 (out-proj f32)
  float*          big2 = (float*)alloc((size_t)2*PAD_*512*4);
  // LQCT: LQ2 (LN out) -> CT2 (attention out)
  unsigned short* LQCT = (unsigned short*)alloc((size_t)2*PAD_*512*2);
  unsigned short* Q2   = (unsigned short*)alloc((size_t)2*PAD_*512*2);

  unsigned short* H12 = big1, *KV2 = big1, *H1o = big1;
  float* T12 = big2; unsigned short* VT2 = (unsigned short*)big2; float* P2 = big2;
  unsigned short* LQ2 = LQCT, *CT2 = LQCT;

  lma_prep_x<<<M_, 256, 0, stream>>>(hidden, Xb);

  {
    TPack tp;
    const float* srcs[14] = { fw[0], fw[2], fw[6], fw[8], fw[10], fw[12],
                              bw[0], bw[2], bw[6], bw[8], bw[10], bw[12],
                              o_w1, o_w2 };
    unsigned short* dsts[14] = { fw1t, fw2t, fqt, fkvt, fkvt + (size_t)512*512, fot,
                                 bw1t, bw2t, bqt, bkvt, bkvt + (size_t)512*512, bot,
                                 ow1t, ow2t };
    int Ks[14] = {1024,1024,512,512,512,512, 1024,1024,512,512,512,512, 1024,1024};
    int Ns[14] = {1024, 512,512,512,512,512, 1024, 512,512,512,512,512, 1024,1024};
    for (int i = 0; i < 14; i++){ tp.src[i]=srcs[i]; tp.dst[i]=dsts[i]; tp.K[i]=Ks[i]; tp.N[i]=Ns[i]; }
    lma_transpose_all<<<dim3(32, 32, 14), 256, 0, stream>>>(tp);
  }
  lma_biascat<<<8, 256, 0, stream>>>(fw[9], fw[11], bw[9], bw[11], biasKV);

  auto G = [&](const unsigned short* A, int lda,
               const unsigned short* B0, const unsigned short* B1,
               const float* b0, const float* b1,
               void* C, int ldc, int M, int N, int K, int mode, int amap){
    lma_gemm2<<<dim3(N/128, (M + 127)/128), 256, 0, stream>>>(A, lda, B0, B1, b0, b1, C, ldc, M, N, K, mode, amap);
  };

  // both-branch FFN + LN + projections (rows<8192 = forward, >=8192 = backward)
  G(Xb, 1024, fw1t, bw1t, fw[1], bw[1], H12, 1024, 2*PAD_, 1024, 1024, 2, 1);  // FFN1+gelu
  G(H12, 1024, fw2t, bw2t, fw[3], bw[3], T12, 512, 2*PAD_, 512, 1024, 3, 0);   // FFN2 -> f32
  lma_ln2<<<2*M_, 256, 0, stream>>>(T12, fw[4], fw[5], bw[4], bw[5], LQ2);
  G(LQ2, 512, fqt, bqt, fw[7], bw[7], Q2, 512, 2*PAD_, 512, 512, 1, 0);        // Q (x0.125)
  G(Xb, 1024, fkvt, bkvt, biasKV, biasKV + 1024, KV2, 1024, 2*PAD_, 1024, 512, 0, 2); // K|V
  lma_vt2<<<dim3(32, 16, 16), 256, 0, stream>>>(KV2, VT2);

  lma_attn3<<<dim3(2048), 256, 0, stream>>>(Q2, KV2, VT2, CT2, lens);

  G(CT2, 512, fot, bot, fw[13], bw[13], P2, 512, 2*PAD_, 512, 512, 3, 0);      // out proj -> f32

  lma_attn_ln<<<M_, 256, 0, stream>>>(P2, P2 + (size_t)PAD_*512, hidden, attn_g, attn_b, Xb);

  G(Xb, 1024, ow1t, ow1t, o_b1, o_b1, H1o, 1024, M_, 1024, 1024, 2, 0);        // out FFN1+gelu
  G(H1o, 1024, ow2t, ow2t, o_b2, o_b2, (float*)d_out, 1024, M_, 1024, 1024, 4, 0); // out FFN2 -> d_out (remapped)
  lma_ln<<<M_, 256, 0, stream>>>((float*)d_out, o_lng, o_lnb, 1024, nullptr, (float*)d_out);
}

// Round 7
// 688.199 us; speedup vs baseline: 1.4416x; 1.1462x over previous
//
#include <hip/hip_runtime.h>
#include <cmath>

#define S_ 1024
#define B_ 8
#define H_ 512
#define S2_ 1022
#define M_ (B_*S2_)     // 8176
#define PAD_ 8192
#define VTS_ ((size_t)8*8*64*1024)   // VT per-branch stride (4194304 shorts)

typedef __attribute__((ext_vector_type(8))) short bf16x8;
typedef __attribute__((ext_vector_type(4))) float f32x4;
typedef __attribute__((ext_vector_type(4))) unsigned int u32x4;
typedef __attribute__((ext_vector_type(2))) unsigned int u32x2;

__device__ __forceinline__ unsigned short f2bf(float f){
  unsigned int u = __float_as_uint(f);
  return (unsigned short)((u + 0x7fffu + ((u>>16)&1u)) >> 16);
}

__device__ __forceinline__ void glds16(const void* g, void* l){
  __builtin_amdgcn_global_load_lds((const __attribute__((address_space(1))) unsigned int*)g,
                                   (__attribute__((address_space(3))) unsigned int*)l, 16, 0, 0);
}

// ---------------------------------------------------------------- prep: X = [f[:-2], bk[2:]] bf16 (M_ x 1024)
__global__ __launch_bounds__(256) void lma_prep_x(const float* __restrict__ hidden,
                                                  unsigned short* __restrict__ Xb){
  int m = blockIdx.x; int dq = threadIdx.x * 4;
  int b = m / S2_, s = m - b * S2_;
  int srow = (dq < 512) ? s : (s + 2);
  const float* src = hidden + ((size_t)srow * B_ + b) * 1024 + dq;
  f32x4 v = *(const f32x4*)src;
  union { u32x2 u; unsigned short s4[4]; } pk;
  #pragma unroll
  for (int j = 0; j < 4; j++) pk.s4[j] = f2bf(v[j]);
  *(u32x2*)&Xb[(size_t)m * 1024 + dq] = pk.u;
}

// ---------------------------------------------------------------- batched weight transpose+cast
struct TPack {
  const float* src[14];
  unsigned short* dst[14];
  int K[14];
  int N[14];
};
__global__ __launch_bounds__(256) void lma_transpose_all(TPack p){
  int idx = blockIdx.z;
  int K = p.K[idx], N = p.N[idx];
  int kb = blockIdx.x * 32, nb = blockIdx.y * 32;
  if (kb >= K || nb >= N) return;
  const float* W = p.src[idx];
  unsigned short* WT = p.dst[idx];
  __shared__ float t[32][33];
  int tx = threadIdx.x & 31, ty = threadIdx.x >> 5;
  #pragma unroll
  for (int i = ty; i < 32; i += 8) t[i][tx] = W[(size_t)(kb + i) * N + nb + tx];
  __syncthreads();
  #pragma unroll
  for (int i = ty; i < 32; i += 8) WT[(size_t)(nb + i) * K + kb + tx] = f2bf(t[tx][i]);
}

// ---------------------------------------------------------------- concat K/V biases
__global__ __launch_bounds__(256) void lma_biascat(const float* __restrict__ fk, const float* __restrict__ fv,
                                                   const float* __restrict__ bk, const float* __restrict__ bv,
                                                   float* __restrict__ out){
  int i = blockIdx.x * 256 + threadIdx.x;     // 0..2047
  int fb = i >> 10, col = i & 1023;
  const float* s = (col < 512) ? (fb ? bk : fk) : (fb ? bv : fv);
  out[i] = s[col & 511];
}

// ---------------------------------------------------------------- V (in KV2, cols 512..1023) -> VT2[fb][b][h][d][s pad 1024]
// Pad cols s in [S2_,1024) ZEROED (aliased buffer may hold bf16-NaN bit patterns).
__global__ __launch_bounds__(256) void lma_vt2(const unsigned short* __restrict__ KV2,
                                               unsigned short* __restrict__ VT2){
  __shared__ unsigned short t[32][34];
  int s0 = blockIdx.x * 32, c0 = blockIdx.y * 32;
  int z = blockIdx.z, fb = z >> 3, b = z & 7;
  const unsigned short* V = KV2 + (size_t)fb * PAD_ * 1024 + 512;
  unsigned short* VT = VT2 + (size_t)fb * VTS_;
  int tx = threadIdx.x & 31, ty = threadIdx.x >> 5;
  #pragma unroll
  for (int i = ty; i < 32; i += 8){
    int s = s0 + i; if (s > S2_-1) s = S2_-1;
    t[i][tx] = V[((size_t)b * S2_ + s) * 1024 + c0 + tx];
  }
  __syncthreads();
  int s = s0 + tx;
  #pragma unroll
  for (int i = ty; i < 32; i += 8){
    int c = c0 + i, h = c >> 6, d = c & 63;
    VT[(((size_t)b * 8 + h) * 64 + d) * 1024 + s] = (s < S2_) ? t[tx][i] : (unsigned short)0;
  }
}

// ---------------------------------------------------------------- branch-combined GEMM (as round 6)
__global__ __launch_bounds__(256) void lma_gemm2(
    const unsigned short* __restrict__ A, int lda,
    const unsigned short* __restrict__ Bt0, const unsigned short* __restrict__ Bt1,
    const float* __restrict__ bias0, const float* __restrict__ bias1,
    void* __restrict__ Cout, int ldc,
    int M, int N, int K, int mode, int amap)
{
  __shared__ unsigned short Al[128*32];
  __shared__ unsigned short Bl[128*32];
  const int tid = threadIdx.x;
  const int w = tid >> 6, lane = tid & 63, quad = lane >> 4, l16 = lane & 15;
  const int m0 = blockIdx.y * 128, n0 = blockIdx.x * 128;
  const int brch = m0 >> 13;
  const unsigned short* Bt = brch ? Bt1 : Bt0;
  const float* bias = brch ? bias1 : bias0;
  const int coloff = (amap == 2 && brch) ? 512 : 0;
  const int wm = (w >> 1) * 64, wn = (w & 1) * 64;

  f32x4 acc[4][4];
  #pragma unroll
  for (int i = 0; i < 4; i++)
    #pragma unroll
    for (int f = 0; f < 4; f++) acc[i][f] = f32x4{0.f,0.f,0.f,0.f};

  const int srow = lane >> 2;
  const int spc  = (lane & 3) * 8;

  for (int k0 = 0; k0 < K; k0 += 32) {
    #pragma unroll
    for (int c = 0; c < 2; c++) {
      int ra = w*32 + c*16 + srow;
      int ga = m0 + ra;
      int ar;
      if (amap == 0) { ar = (ga > M-1) ? (M-1) : ga; }
      else { ar = ga & (PAD_-1); if (ar > M_-1) ar = M_-1; }
      glds16(A + (size_t)ar * lda + coloff + k0 + spc, &Al[(w*32 + c*16) * 32]);
      int gb = n0 + ra; if (gb > N-1) gb = N-1;
      glds16(Bt + (size_t)gb * K + k0 + spc, &Bl[(w*32 + c*16) * 32]);
    }
    __syncthreads();
    bf16x8 af[4], bfr[4];
    #pragma unroll
    for (int i = 0; i < 4; i++) af[i]  = *(const bf16x8*)&Al[(wm + i*16 + l16)*32 + quad*8];
    #pragma unroll
    for (int f = 0; f < 4; f++) bfr[f] = *(const bf16x8*)&Bl[(wn + f*16 + l16)*32 + quad*8];
    #pragma unroll
    for (int i = 0; i < 4; i++)
      #pragma unroll
      for (int f = 0; f < 4; f++)
        acc[i][f] = __builtin_amdgcn_mfma_f32_16x16x32_bf16(af[i], bfr[f], acc[i][f], 0, 0, 0);
    __syncthreads();
  }

  #pragma unroll
  for (int f = 0; f < 4; f++) {
    int col = n0 + wn + f*16 + l16;
    float bv = bias ? bias[col] : 0.f;
    #pragma unroll
    for (int i = 0; i < 4; i++) {
      #pragma unroll
      for (int r = 0; r < 4; r++) {
        int row = m0 + wm + i*16 + quad*4 + r;
        if (row < M) {
          float v = acc[i][f][r] + bv;
          if (mode == 2) v = 0.5f * v * (1.f + erff(v * 0.70710678118654752f));
          else if (mode == 1) v *= 0.125f;
          if (mode <= 2) ((unsigned short*)Cout)[(size_t)row * ldc + col] = f2bf(v);
          else if (mode == 3) ((float*)Cout)[(size_t)row * ldc + col] = v;
          else {
            int sr = row % S2_, bb2 = row / S2_;
            ((float*)Cout)[((size_t)sr * B_ + bb2) * ldc + col] = v;
          }
        }
      }
    }
  }
}

// ---------------------------------------------------------------- block reduction helper
__device__ __forceinline__ void lma_red2(float& s, float& sq){
  __shared__ float red[16];
  #pragma unroll
  for (int msk = 1; msk < 64; msk <<= 1){ s += __shfl_xor(s, msk); sq += __shfl_xor(sq, msk); }
  int w = threadIdx.x >> 6;
  if ((threadIdx.x & 63) == 0){ red[w] = s; red[8 + w] = sq; }
  __syncthreads();
  s  = red[0] + red[1] + red[2] + red[3];
  sq = red[8] + red[9] + red[10] + red[11];
}

// ---------------------------------------------------------------- generic LN (f32 in, bf16 or f32 out)
__global__ __launch_bounds__(256) void lma_ln(const float* __restrict__ in,
                                              const float* __restrict__ g, const float* __restrict__ bb,
                                              int D, unsigned short* __restrict__ obf, float* __restrict__ of32){
  int row = blockIdx.x, t = threadIdx.x;
  const float* x = in + (size_t)row * D;
  float s = 0.f, sq = 0.f;
  for (int d = t; d < D; d += 256){ float v = x[d]; s += v; sq += v * v; }
  lma_red2(s, sq);
  float mean = s / D;
  float var = sq / D - mean * mean;
  float rstd = rsqrtf(fmaxf(var, 0.f) + 1e-12f);
  if (obf) {
    for (int d = t; d < D; d += 256) obf[(size_t)row * D + d] = f2bf((x[d] - mean) * rstd * g[d] + bb[d]);
  } else {
    for (int d = t; d < D; d += 256) of32[(size_t)row * D + d] = (x[d] - mean) * rstd * g[d] + bb[d];
  }
}

// ---------------------------------------------------------------- branch-combined LN over T12 (D=512) -> LQ2 bf16
__global__ __launch_bounds__(256) void lma_ln2(const float* __restrict__ T12,
                                               const float* __restrict__ fg, const float* __restrict__ fbb,
                                               const float* __restrict__ bg, const float* __restrict__ bbb,
                                               unsigned short* __restrict__ LQ2){
  int m = blockIdx.x, t = threadIdx.x;           // 0..2*M_-1
  int fb = (m >= M_);
  int idx = m - fb * M_;
  const float* g = fb ? bg : fg;
  const float* bb = fb ? bbb : fbb;
  const float* x = T12 + ((size_t)fb * PAD_ + idx) * 512;
  unsigned short* o = LQ2 + ((size_t)fb * PAD_ + idx) * 512;
  float v0 = x[t], v1 = x[t + 256];
  float s = v0 + v1, sq = v0*v0 + v1*v1;
  lma_red2(s, sq);
  float mean = s / 512.f;
  float var = sq / 512.f - mean * mean;
  float rstd = rsqrtf(fmaxf(var, 0.f) + 1e-12f);
  o[t]       = f2bf((v0 - mean) * rstd * g[t]       + bb[t]);
  o[t + 256] = f2bf((v1 - mean) * rstd * g[t + 256] + bb[t + 256]);
}

// ---------------------------------------------------------------- attn LN: LN(residual(hidden)+[pf,pb]) -> bf16 (M_ x 1024)
__global__ __launch_bounds__(256) void lma_attn_ln(const float* __restrict__ pf, const float* __restrict__ pb,
                                                   const float* __restrict__ hidden,
                                                   const float* __restrict__ g, const float* __restrict__ bb,
                                                   unsigned short* __restrict__ out){
  int m = blockIdx.x, t = threadIdx.x;
  int b = m / S2_, s = m - b * S2_;
  const float* hf = hidden + ((size_t)s       * B_ + b) * 1024;
  const float* hb = hidden + ((size_t)(s + 2) * B_ + b) * 1024;
  float v[4]; float sum = 0.f, sq = 0.f;
  #pragma unroll
  for (int j = 0; j < 4; j++){
    int d = t + j * 256;
    float x = (d < 512) ? (pf[(size_t)m * 512 + d] + hf[d])
                        : (pb[(size_t)m * 512 + (d - 512)] + hb[d]);
    v[j] = x; sum += x; sq += x * x;
  }
  lma_red2(sum, sq);
  float mean = sum / 1024.f;
  float var = sq / 1024.f - mean * mean;
  float rstd = rsqrtf(fmaxf(var, 0.f) + 1e-12f);
  #pragma unroll
  for (int j = 0; j < 4; j++){
    int d = t + j * 256;
    out[(size_t)m * 1024 + d] = f2bf((v[j] - mean) * rstd * g[d] + bb[d]);
  }
}

// ---------------------------------------------------------------- combined flash attention v4: LDS-staged K/VT tiles.
// id = fb*1024 + qt*64 + h*8 + b => id%8=b (XCD locality). Block stages the
// 64x64 K-tile + 64x64 VT-tile ONCE via global_load_lds (coalesced, 4x less
// L1/L2 traffic than per-wave fragment loads), XOR-swizzled (slot g = g0 ^
// (row&7)) so ds_read_b128 fragment reads are 2-way (free) not 16-way.
// Block-uniform k-range pruning; 2 barriers per tile; DMA latency hidden by
// 4+ resident blocks/CU.
#define PSTR 80
__global__ __launch_bounds__(256, 4) void lma_attn4(const unsigned short* __restrict__ Q2,
                                                    const unsigned short* __restrict__ KV2,
                                                    const unsigned short* __restrict__ VT2,
                                                    unsigned short* __restrict__ CT2,
                                                    const int* __restrict__ lens){
  __shared__ unsigned short Kl[64*64];
  __shared__ unsigned short Vl[64*64];
  __shared__ __align__(16) unsigned short Pl[4][16*PSTR];

  const int tid = threadIdx.x;
  const int w = tid >> 6, lane = tid & 63, quad = lane >> 4, l16 = lane & 15;
  const int id = blockIdx.x;
  const int fb = id >> 10, rid = id & 1023;
  const int qt = rid >> 6, h = (rid >> 3) & 7, b = rid & 7;
  const int backward = fb;
  const int L2 = lens[b] - 2;
  const int q0wg = qt * 64;
  const int q0 = q0wg + w * 16;
  const int qg = q0 + l16;
  const int qload = (qg > S2_-1) ? (S2_-1) : qg;

  const unsigned short* Q  = Q2  + (size_t)fb * PAD_ * 512;
  const unsigned short* Kx = KV2 + (size_t)fb * PAD_ * 1024;
  const unsigned short* VT = VT2 + (size_t)fb * VTS_;
  unsigned short* CTX      = CT2 + (size_t)fb * PAD_ * 512;
  const size_t qbase  = ((size_t)b * S2_) * 512  + h * 64;   // Q/CT rows, stride 512
  const size_t kbase  = ((size_t)b * S2_) * 1024 + h * 64;   // K rows inside KV2, stride 1024
  const size_t vtbase = ((size_t)(b * 8 + h) * 64) * 1024;
  unsigned short* Pw = &Pl[w][0];

  // staging constants: each glds16 covers 8 rows (8 lanes/row, 16B/lane).
  // slot colgrp = lane&7; stored element's source colgrp g0 = (lane&7)^(lane>>3)
  // (row&7 == lane>>3 since bases are multiples of 8).
  const int lrow = lane >> 3;
  const int g0s  = (lane & 7) ^ lrow;
  const int x7   = l16 & 7;    // fragment-read xor key (row&7 == l16&7)

  bf16x8 qf[2];
  {
    const unsigned short* qp = Q + qbase + (size_t)qload * 512 + quad * 8;
    qf[0] = *(const bf16x8*)(qp);
    qf[1] = *(const bf16x8*)(qp + 32);
  }

  float mi = -3e38f, li = 0.f;
  f32x4 ot[4];
  #pragma unroll
  for (int f = 0; f < 4; f++) ot[f] = f32x4{0.f,0.f,0.f,0.f};

  // block-uniform key-range pruning
  int klo = 0, khi = S2_ - 1;
  if (q0wg + 63 < L2) {
    if (!backward) khi = q0wg + 63;
    else { klo = q0wg; khi = L2 - 1; }
  }

  for (int kt0 = klo; kt0 <= khi; kt0 += 64) {
    // --- stage K-tile and VT-tile into LDS (each wave: 16 rows via 2 calls each)
    #pragma unroll
    for (int c = 0; c < 2; c++) {
      int r = w*16 + c*8 + lrow;                 // tile row 0..63
      int kr = kt0 + r; if (kr > S2_-1) kr = S2_-1;
      glds16(Kx + kbase + (size_t)kr * 1024 + g0s * 8, &Kl[(w*16 + c*8) * 64]);
      glds16(VT + vtbase + (size_t)r * 1024 + kt0 + g0s * 8, &Vl[(w*16 + c*8) * 64]);
    }
    __syncthreads();

    // --- fragment reads (swizzled): source colgrp g -> slot g ^ (row&7)
    bf16x8 kf[4][2], vf[4][2];
    #pragma unroll
    for (int sub = 0; sub < 4; sub++) {
      const unsigned short* kp = &Kl[(sub*16 + l16) * 64];
      kf[sub][0] = *(const bf16x8*)(kp + (( quad      ^ x7) * 8));
      kf[sub][1] = *(const bf16x8*)(kp + (((quad + 4) ^ x7) * 8));
    }
    #pragma unroll
    for (int f = 0; f < 4; f++) {
      const unsigned short* vp = &Vl[(f*16 + l16) * 64];
      vf[f][0] = *(const bf16x8*)(vp + (( quad      ^ x7) * 8));
      vf[f][1] = *(const bf16x8*)(vp + (((quad + 4) ^ x7) * 8));
    }

    // --- S^T = K . Q^T
    f32x4 st[4];
    #pragma unroll
    for (int sub = 0; sub < 4; sub++) {
      f32x4 s = f32x4{0.f,0.f,0.f,0.f};
      s = __builtin_amdgcn_mfma_f32_16x16x32_bf16(kf[sub][0], qf[0], s, 0, 0, 0);
      s = __builtin_amdgcn_mfma_f32_16x16x32_bf16(kf[sub][1], qf[1], s, 0, 0, 0);
      st[sub] = s;
    }

    // --- mask
    #pragma unroll
    for (int sub = 0; sub < 4; sub++) {
      #pragma unroll
      for (int r = 0; r < 4; r++) {
        int kg = kt0 + sub*16 + quad*4 + r;
        bool ok;
        if (!backward) ok = (kg < S2_) && ((qg >= L2) || (kg <= qg));
        else           ok = (kg < S2_) && ((qg >= L2) || ((kg >= qg) && (kg < L2)));
        if (!ok) st[sub][r] = -3e38f;
      }
    }

    // --- online softmax
    float mx = -3e38f;
    #pragma unroll
    for (int sub = 0; sub < 4; sub++)
      #pragma unroll
      for (int r = 0; r < 4; r++) mx = fmaxf(mx, st[sub][r]);
    mx = fmaxf(mx, __shfl_xor(mx, 16));
    mx = fmaxf(mx, __shfl_xor(mx, 32));
    float mn = fmaxf(mi, mx);
    float alpha = __expf(mi - mn);
    mi = mn;
    float rs = 0.f;
    #pragma unroll
    for (int sub = 0; sub < 4; sub++)
      #pragma unroll
      for (int r = 0; r < 4; r++) {
        float p = __expf(st[sub][r] - mn);
        st[sub][r] = p; rs += p;
      }
    rs += __shfl_xor(rs, 16);
    rs += __shfl_xor(rs, 32);
    li = li * alpha + rs;
    #pragma unroll
    for (int f = 0; f < 4; f++)
      #pragma unroll
      for (int r = 0; r < 4; r++) ot[f][r] *= alpha;

    // --- P round-trip (per-wave region, DS in-order, no barrier)
    #pragma unroll
    for (int sub = 0; sub < 4; sub++) {
      ushort4 pk;
      pk.x = f2bf(st[sub][0]); pk.y = f2bf(st[sub][1]);
      pk.z = f2bf(st[sub][2]); pk.w = f2bf(st[sub][3]);
      *(ushort4*)&Pw[l16*PSTR + sub*16 + quad*4] = pk;
    }
    bf16x8 pfr0 = *(const bf16x8*)&Pw[l16*PSTR +      quad*8];
    bf16x8 pfr1 = *(const bf16x8*)&Pw[l16*PSTR + 32 + quad*8];

    // --- O^T += V^T . P^T
    #pragma unroll
    for (int f = 0; f < 4; f++) {
      ot[f] = __builtin_amdgcn_mfma_f32_16x16x32_bf16(vf[f][0], pfr0, ot[f], 0, 0, 0);
      ot[f] = __builtin_amdgcn_mfma_f32_16x16x32_bf16(vf[f][1], pfr1, ot[f], 0, 0, 0);
    }
    __syncthreads();
  }

  if (qg < S2_) {
    float rcp = 1.f / li;
    #pragma unroll
    for (int f = 0; f < 4; f++) {
      ushort4 pk;
      pk.x = f2bf(ot[f][0] * rcp); pk.y = f2bf(ot[f][1] * rcp);
      pk.z = f2bf(ot[f][2] * rcp); pk.w = f2bf(ot[f][3] * rcp);
      *(ushort4*)&CTX[qbase + (size_t)qg * 512 + f*16 + quad*4] = pk;
    }
  }
}

// ----------------------------------------------------------------
extern "C" void kernel_launch(void* const* d_in, const int* in_sizes, int n_in,
                              void* d_out, int out_size, void* d_ws, size_t ws_size,
                              hipStream_t stream)
{
  const float* hidden = (const float*)d_in[0];
  const int*   lens   = (const int*)d_in[1];
  const float* fw[14]; for (int i = 0; i < 14; i++) fw[i] = (const float*)d_in[2 + i];
  const float* bw[14]; for (int i = 0; i < 14; i++) bw[i] = (const float*)d_in[16 + i];
  const float* attn_g = (const float*)d_in[30];
  const float* attn_b = (const float*)d_in[31];
  const float* o_w1 = (const float*)d_in[32];
  const float* o_b1 = (const float*)d_in[33];
  const float* o_w2 = (const float*)d_in[34];
  const float* o_b2 = (const float*)d_in[35];
  const float* o_lng = (const float*)d_in[36];
  const float* o_lnb = (const float*)d_in[37];

  char* ws = (char*)d_ws;
  size_t off = 0;
  auto alloc = [&](size_t bytes)->char* {
    off = (off + 255) & ~(size_t)255;
    char* p = ws + off; off += bytes; return p;
  };

  unsigned short* fw1t = (unsigned short*)alloc((size_t)1024*1024*2);
  unsigned short* fw2t = (unsigned short*)alloc((size_t)512*1024*2);
  unsigned short* fqt  = (unsigned short*)alloc((size_t)512*512*2);
  unsigned short* fkvt = (unsigned short*)alloc((size_t)1024*512*2);  // [K(512 rows); V(512 rows)]
  unsigned short* fot  = (unsigned short*)alloc((size_t)512*512*2);
  unsigned short* bw1t = (unsigned short*)alloc((size_t)1024*1024*2);
  unsigned short* bw2t = (unsigned short*)alloc((size_t)512*1024*2);
  unsigned short* bqt  = (unsigned short*)alloc((size_t)512*512*2);
  unsigned short* bkvt = (unsigned short*)alloc((size_t)1024*512*2);
  unsigned short* bot  = (unsigned short*)alloc((size_t)512*512*2);
  unsigned short* ow1t = (unsigned short*)alloc((size_t)1024*1024*2);
  unsigned short* ow2t = (unsigned short*)alloc((size_t)1024*1024*2);
  float*          biasKV = (float*)alloc(2048*4);

  unsigned short* Xb   = (unsigned short*)alloc((size_t)M_*1024*2);
  unsigned short* big1 = (unsigned short*)alloc((size_t)2*PAD_*1024*2);
  float*          big2 = (float*)alloc((size_t)2*PAD_*512*4);
  unsigned short* LQCT = (unsigned short*)alloc((size_t)2*PAD_*512*2);
  unsigned short* Q2   = (unsigned short*)alloc((size_t)2*PAD_*512*2);

  unsigned short* H12 = big1, *KV2 = big1, *H1o = big1;
  float* T12 = big2; unsigned short* VT2 = (unsigned short*)big2; float* P2 = big2;
  unsigned short* LQ2 = LQCT, *CT2 = LQCT;

  lma_prep_x<<<M_, 256, 0, stream>>>(hidden, Xb);

  {
    TPack tp;
    const float* srcs[14] = { fw[0], fw[2], fw[6], fw[8], fw[10], fw[12],
                              bw[0], bw[2], bw[6], bw[8], bw[10], bw[12],
                              o_w1, o_w2 };
    unsigned short* dsts[14] = { fw1t, fw2t, fqt, fkvt, fkvt + (size_t)512*512, fot,
                                 bw1t, bw2t, bqt, bkvt, bkvt + (size_t)512*512, bot,
                                 ow1t, ow2t };
    int Ks[14] = {1024,1024,512,512,512,512, 1024,1024,512,512,512,512, 1024,1024};
    int Ns[14] = {1024, 512,512,512,512,512, 1024, 512,512,512,512,512, 1024,1024};
    for (int i = 0; i < 14; i++){ tp.src[i]=srcs[i]; tp.dst[i]=dsts[i]; tp.K[i]=Ks[i]; tp.N[i]=Ns[i]; }
    lma_transpose_all<<<dim3(32, 32, 14), 256, 0, stream>>>(tp);
  }
  lma_biascat<<<8, 256, 0, stream>>>(fw[9], fw[11], bw[9], bw[11], biasKV);

  auto G = [&](const unsigned short* A, int lda,
               const unsigned short* B0, const unsigned short* B1,
               const float* b0, const float* b1,
               void* C, int ldc, int M, int N, int K, int mode, int amap){
    lma_gemm2<<<dim3(N/128, (M + 127)/128), 256, 0, stream>>>(A, lda, B0, B1, b0, b1, C, ldc, M, N, K, mode, amap);
  };

  // both-branch FFN + LN + projections (rows<8192 = forward, >=8192 = backward)
  G(Xb, 1024, fw1t, bw1t, fw[1], bw[1], H12, 1024, 2*PAD_, 1024, 1024, 2, 1);  // FFN1+gelu
  G(H12, 1024, fw2t, bw2t, fw[3], bw[3], T12, 512, 2*PAD_, 512, 1024, 3, 0);   // FFN2 -> f32
  lma_ln2<<<2*M_, 256, 0, stream>>>(T12, fw[4], fw[5], bw[4], bw[5], LQ2);
  G(LQ2, 512, fqt, bqt, fw[7], bw[7], Q2, 512, 2*PAD_, 512, 512, 1, 0);        // Q (x0.125)
  G(Xb, 1024, fkvt, bkvt, biasKV, biasKV + 1024, KV2, 1024, 2*PAD_, 1024, 512, 0, 2); // K|V
  lma_vt2<<<dim3(32, 16, 16), 256, 0, stream>>>(KV2, VT2);

  lma_attn4<<<dim3(2048), 256, 0, stream>>>(Q2, KV2, VT2, CT2, lens);

  G(CT2, 512, fot, bot, fw[13], bw[13], P2, 512, 2*PAD_, 512, 512, 3, 0);      // out proj -> f32

  lma_attn_ln<<<M_, 256, 0, stream>>>(P2, P2 + (size_t)PAD_*512, hidden, attn_g, attn_b, Xb);

  G(Xb, 1024, ow1t, ow1t, o_b1, o_b1, H1o, 1024, M_, 1024, 1024, 2, 0);        // out FFN1+gelu
  G(H1o, 1024, ow2t, ow2t, o_b2, o_b2, (float*)d_out, 1024, M_, 1024, 1024, 4, 0); // out FFN2 -> d_out (remapped)
  lma_ln<<<M_, 256, 0, stream>>>((float*)d_out, o_lng, o_lnb, 1024, nullptr, (float*)d_out);
}

// Round 8
// 642.580 us; speedup vs baseline: 1.5439x; 1.0710x over previous
//
#include <hip/hip_runtime.h>
#include <cmath>

#define S_ 1024
#define B_ 8
#define H_ 512
#define S2_ 1022
#define M_ (B_*S2_)     // 8176
#define PAD_ 8192
#define VTS_ ((size_t)8*8*64*1024)   // VT per-branch stride (4194304 shorts)

typedef __attribute__((ext_vector_type(8))) short bf16x8;
typedef __attribute__((ext_vector_type(4))) float f32x4;
typedef __attribute__((ext_vector_type(4))) unsigned int u32x4;
typedef __attribute__((ext_vector_type(2))) unsigned int u32x2;

__device__ __forceinline__ unsigned short f2bf(float f){
  unsigned int u = __float_as_uint(f);
  return (unsigned short)((u + 0x7fffu + ((u>>16)&1u)) >> 16);
}
__device__ __forceinline__ float bf2f(unsigned short u){
  return __uint_as_float((unsigned int)u << 16);
}
// tanh-approx gelu: x*sigmoid(2*(c1 x + c2 x^3)); |err vs erf-gelu| < ~3e-4
__device__ __forceinline__ float fgelu(float x){
  float u = x * (0.7978845608f + 0.0356774081f * x * x);
  return x / (1.f + __expf(-2.f * u));
}

__device__ __forceinline__ void glds16(const void* g, void* l){
  __builtin_amdgcn_global_load_lds((const __attribute__((address_space(1))) unsigned int*)g,
                                   (__attribute__((address_space(3))) unsigned int*)l, 16, 0, 0);
}

// ---------------------------------------------------------------- prep: X = [f[:-2], bk[2:]] bf16 (M_ x 1024)
__global__ __launch_bounds__(256) void lma_prep_x(const float* __restrict__ hidden,
                                                  unsigned short* __restrict__ Xb){
  int m = blockIdx.x; int dq = threadIdx.x * 4;
  int b = m / S2_, s = m - b * S2_;
  int srow = (dq < 512) ? s : (s + 2);
  const float* src = hidden + ((size_t)srow * B_ + b) * 1024 + dq;
  f32x4 v = *(const f32x4*)src;
  union { u32x2 u; unsigned short s4[4]; } pk;
  #pragma unroll
  for (int j = 0; j < 4; j++) pk.s4[j] = f2bf(v[j]);
  *(u32x2*)&Xb[(size_t)m * 1024 + dq] = pk.u;
}

// ---------------------------------------------------------------- batched weight transpose+cast
struct TPack {
  const float* src[14];
  unsigned short* dst[14];
  int K[14];
  int N[14];
};
__global__ __launch_bounds__(256) void lma_transpose_all(TPack p){
  int idx = blockIdx.z;
  int K = p.K[idx], N = p.N[idx];
  int kb = blockIdx.x * 32, nb = blockIdx.y * 32;
  if (kb >= K || nb >= N) return;
  const float* W = p.src[idx];
  unsigned short* WT = p.dst[idx];
  __shared__ float t[32][33];
  int tx = threadIdx.x & 31, ty = threadIdx.x >> 5;
  #pragma unroll
  for (int i = ty; i < 32; i += 8) t[i][tx] = W[(size_t)(kb + i) * N + nb + tx];
  __syncthreads();
  #pragma unroll
  for (int i = ty; i < 32; i += 8) WT[(size_t)(nb + i) * K + kb + tx] = f2bf(t[tx][i]);
}

// ---------------------------------------------------------------- concat K/V biases
__global__ __launch_bounds__(256) void lma_biascat(const float* __restrict__ fk, const float* __restrict__ fv,
                                                   const float* __restrict__ bk, const float* __restrict__ bv,
                                                   float* __restrict__ out){
  int i = blockIdx.x * 256 + threadIdx.x;     // 0..2047
  int fb = i >> 10, col = i & 1023;
  const float* s = (col < 512) ? (fb ? bk : fk) : (fb ? bv : fv);
  out[i] = s[col & 511];
}

// ---------------------------------------------------------------- V (in KV2, cols 512..1023) -> VT2[fb][b][h][d][s pad 1024]
// Pad cols s in [S2_,1024) ZEROED (aliased buffer may hold bf16-NaN bit patterns).
__global__ __launch_bounds__(256) void lma_vt2(const unsigned short* __restrict__ KV2,
                                               unsigned short* __restrict__ VT2){
  __shared__ unsigned short t[32][34];
  int s0 = blockIdx.x * 32, c0 = blockIdx.y * 32;
  int z = blockIdx.z, fb = z >> 3, b = z & 7;
  const unsigned short* V = KV2 + (size_t)fb * PAD_ * 1024 + 512;
  unsigned short* VT = VT2 + (size_t)fb * VTS_;
  int tx = threadIdx.x & 31, ty = threadIdx.x >> 5;
  #pragma unroll
  for (int i = ty; i < 32; i += 8){
    int s = s0 + i; if (s > S2_-1) s = S2_-1;
    t[i][tx] = V[((size_t)b * S2_ + s) * 1024 + c0 + tx];
  }
  __syncthreads();
  int s = s0 + tx;
  #pragma unroll
  for (int i = ty; i < 32; i += 8){
    int c = c0 + i, h = c >> 6, d = c & 63;
    VT[(((size_t)b * 8 + h) * 64 + d) * 1024 + s] = (s < S2_) ? t[tx][i] : (unsigned short)0;
  }
}

// ---------------------------------------------------------------- branch-combined GEMM, flat grid + XCD-reuse swizzle
// id: mt = id % nmt (m-tile FASTEST; nmt always multiple of 8 => all n-tile
// readers of A-tile mt have id%8 = mt%8 -> same XCD -> A fetched once/XCD).
// rows < 8192 use (Bt0,bias0), rows >= 8192 use (Bt1,bias1).
// amap: 0 direct (clamp M-1) | 1 row=(r&8191) clamp M_-1 | 2 like 1 + +512 col for branch 1
// modes: 0 bf16 bias | 1 bf16 bias*0.125 | 2 bf16 bias+gelu(tanh) | 3 f32 bias | 4 f32 bias row-remap (s*B+b)
__global__ __launch_bounds__(256) void lma_gemm2(
    const unsigned short* __restrict__ A, int lda,
    const unsigned short* __restrict__ Bt0, const unsigned short* __restrict__ Bt1,
    const float* __restrict__ bias0, const float* __restrict__ bias1,
    void* __restrict__ Cout, int ldc,
    int M, int N, int K, int mode, int amap, int nmt)
{
  __shared__ unsigned short Al[128*32];
  __shared__ unsigned short Bl[128*32];
  const int tid = threadIdx.x;
  const int w = tid >> 6, lane = tid & 63, quad = lane >> 4, l16 = lane & 15;
  const int mt = blockIdx.x % nmt, nt = blockIdx.x / nmt;
  const int m0 = mt * 128, n0 = nt * 128;
  const int brch = m0 >> 13;
  const unsigned short* Bt = brch ? Bt1 : Bt0;
  const float* bias = brch ? bias1 : bias0;
  const int coloff = (amap == 2 && brch) ? 512 : 0;
  const int wm = (w >> 1) * 64, wn = (w & 1) * 64;

  f32x4 acc[4][4];
  #pragma unroll
  for (int i = 0; i < 4; i++)
    #pragma unroll
    for (int f = 0; f < 4; f++) acc[i][f] = f32x4{0.f,0.f,0.f,0.f};

  const int srow = lane >> 2;
  const int spc  = (lane & 3) * 8;

  for (int k0 = 0; k0 < K; k0 += 32) {
    #pragma unroll
    for (int c = 0; c < 2; c++) {
      int ra = w*32 + c*16 + srow;
      int ga = m0 + ra;
      int ar;
      if (amap == 0) { ar = (ga > M-1) ? (M-1) : ga; }
      else { ar = ga & (PAD_-1); if (ar > M_-1) ar = M_-1; }
      glds16(A + (size_t)ar * lda + coloff + k0 + spc, &Al[(w*32 + c*16) * 32]);
      int gb = n0 + ra; if (gb > N-1) gb = N-1;
      glds16(Bt + (size_t)gb * K + k0 + spc, &Bl[(w*32 + c*16) * 32]);
    }
    __syncthreads();
    bf16x8 af[4], bfr[4];
    #pragma unroll
    for (int i = 0; i < 4; i++) af[i]  = *(const bf16x8*)&Al[(wm + i*16 + l16)*32 + quad*8];
    #pragma unroll
    for (int f = 0; f < 4; f++) bfr[f] = *(const bf16x8*)&Bl[(wn + f*16 + l16)*32 + quad*8];
    #pragma unroll
    for (int i = 0; i < 4; i++)
      #pragma unroll
      for (int f = 0; f < 4; f++)
        acc[i][f] = __builtin_amdgcn_mfma_f32_16x16x32_bf16(af[i], bfr[f], acc[i][f], 0, 0, 0);
    __syncthreads();
  }

  #pragma unroll
  for (int f = 0; f < 4; f++) {
    int col = n0 + wn + f*16 + l16;
    float bv = bias ? bias[col] : 0.f;
    #pragma unroll
    for (int i = 0; i < 4; i++) {
      #pragma unroll
      for (int r = 0; r < 4; r++) {
        int row = m0 + wm + i*16 + quad*4 + r;
        if (row < M) {
          float v = acc[i][f][r] + bv;
          if (mode == 2) v = fgelu(v);
          else if (mode == 1) v *= 0.125f;
          if (mode <= 2) ((unsigned short*)Cout)[(size_t)row * ldc + col] = f2bf(v);
          else if (mode == 3) ((float*)Cout)[(size_t)row * ldc + col] = v;
          else {
            int sr = row % S2_, bb2 = row / S2_;
            ((float*)Cout)[((size_t)sr * B_ + bb2) * ldc + col] = v;
          }
        }
      }
    }
  }
}

// ---------------------------------------------------------------- block reduction helper
__device__ __forceinline__ void lma_red2(float& s, float& sq){
  __shared__ float red[16];
  #pragma unroll
  for (int msk = 1; msk < 64; msk <<= 1){ s += __shfl_xor(s, msk); sq += __shfl_xor(sq, msk); }
  int w = threadIdx.x >> 6;
  if ((threadIdx.x & 63) == 0){ red[w] = s; red[8 + w] = sq; }
  __syncthreads();
  s  = red[0] + red[1] + red[2] + red[3];
  sq = red[8] + red[9] + red[10] + red[11];
}

// ---------------------------------------------------------------- generic LN (f32 in, bf16 or f32 out)
__global__ __launch_bounds__(256) void lma_ln(const float* __restrict__ in,
                                              const float* __restrict__ g, const float* __restrict__ bb,
                                              int D, unsigned short* __restrict__ obf, float* __restrict__ of32){
  int row = blockIdx.x, t = threadIdx.x;
  const float* x = in + (size_t)row * D;
  float s = 0.f, sq = 0.f;
  for (int d = t; d < D; d += 256){ float v = x[d]; s += v; sq += v * v; }
  lma_red2(s, sq);
  float mean = s / D;
  float var = sq / D - mean * mean;
  float rstd = rsqrtf(fmaxf(var, 0.f) + 1e-12f);
  if (obf) {
    for (int d = t; d < D; d += 256) obf[(size_t)row * D + d] = f2bf((x[d] - mean) * rstd * g[d] + bb[d]);
  } else {
    for (int d = t; d < D; d += 256) of32[(size_t)row * D + d] = (x[d] - mean) * rstd * g[d] + bb[d];
  }
}

// ---------------------------------------------------------------- branch-combined LN over T12b (bf16, D=512) -> LQ2 bf16
__global__ __launch_bounds__(256) void lma_ln2(const unsigned short* __restrict__ T12b,
                                               const float* __restrict__ fg, const float* __restrict__ fbb,
                                               const float* __restrict__ bg, const float* __restrict__ bbb,
                                               unsigned short* __restrict__ LQ2){
  int m = blockIdx.x, t = threadIdx.x;           // 0..2*M_-1
  int fb = (m >= M_);
  int idx = m - fb * M_;
  const float* g = fb ? bg : fg;
  const float* bb = fb ? bbb : fbb;
  const unsigned short* x = T12b + ((size_t)fb * PAD_ + idx) * 512;
  unsigned short* o = LQ2 + ((size_t)fb * PAD_ + idx) * 512;
  float v0 = bf2f(x[t]), v1 = bf2f(x[t + 256]);
  float s = v0 + v1, sq = v0*v0 + v1*v1;
  lma_red2(s, sq);
  float mean = s / 512.f;
  float var = sq / 512.f - mean * mean;
  float rstd = rsqrtf(fmaxf(var, 0.f) + 1e-12f);
  o[t]       = f2bf((v0 - mean) * rstd * g[t]       + bb[t]);
  o[t + 256] = f2bf((v1 - mean) * rstd * g[t + 256] + bb[t + 256]);
}

// ---------------------------------------------------------------- attn LN: LN(residual(hidden)+[pf,pb](bf16)) -> bf16 (M_ x 1024)
__global__ __launch_bounds__(256) void lma_attn_ln(const unsigned short* __restrict__ pf,
                                                   const unsigned short* __restrict__ pb,
                                                   const float* __restrict__ hidden,
                                                   const float* __restrict__ g, const float* __restrict__ bb,
                                                   unsigned short* __restrict__ out){
  int m = blockIdx.x, t = threadIdx.x;
  int b = m / S2_, s = m - b * S2_;
  const float* hf = hidden + ((size_t)s       * B_ + b) * 1024;
  const float* hb = hidden + ((size_t)(s + 2) * B_ + b) * 1024;
  float v[4]; float sum = 0.f, sq = 0.f;
  #pragma unroll
  for (int j = 0; j < 4; j++){
    int d = t + j * 256;
    float x = (d < 512) ? (bf2f(pf[(size_t)m * 512 + d]) + hf[d])
                        : (bf2f(pb[(size_t)m * 512 + (d - 512)]) + hb[d]);
    v[j] = x; sum += x; sq += x * x;
  }
  lma_red2(sum, sq);
  float mean = sum / 1024.f;
  float var = sq / 1024.f - mean * mean;
  float rstd = rsqrtf(fmaxf(var, 0.f) + 1e-12f);
  #pragma unroll
  for (int j = 0; j < 4; j++){
    int d = t + j * 256;
    out[(size_t)m * 1024 + d] = f2bf((v[j] - mean) * rstd * g[d] + bb[d]);
  }
}

// ---------------------------------------------------------------- combined flash attention v4 (round-7, unchanged)
#define PSTR 80
__global__ __launch_bounds__(256, 4) void lma_attn4(const unsigned short* __restrict__ Q2,
                                                    const unsigned short* __restrict__ KV2,
                                                    const unsigned short* __restrict__ VT2,
                                                    unsigned short* __restrict__ CT2,
                                                    const int* __restrict__ lens){
  __shared__ unsigned short Kl[64*64];
  __shared__ unsigned short Vl[64*64];
  __shared__ __align__(16) unsigned short Pl[4][16*PSTR];

  const int tid = threadIdx.x;
  const int w = tid >> 6, lane = tid & 63, quad = lane >> 4, l16 = lane & 15;
  const int id = blockIdx.x;
  const int fb = id >> 10, rid = id & 1023;
  const int qt = rid >> 6, h = (rid >> 3) & 7, b = rid & 7;
  const int backward = fb;
  const int L2 = lens[b] - 2;
  const int q0wg = qt * 64;
  const int q0 = q0wg + w * 16;
  const int qg = q0 + l16;
  const int qload = (qg > S2_-1) ? (S2_-1) : qg;

  const unsigned short* Q  = Q2  + (size_t)fb * PAD_ * 512;
  const unsigned short* Kx = KV2 + (size_t)fb * PAD_ * 1024;
  const unsigned short* VT = VT2 + (size_t)fb * VTS_;
  unsigned short* CTX      = CT2 + (size_t)fb * PAD_ * 512;
  const size_t qbase  = ((size_t)b * S2_) * 512  + h * 64;
  const size_t kbase  = ((size_t)b * S2_) * 1024 + h * 64;
  const size_t vtbase = ((size_t)(b * 8 + h) * 64) * 1024;
  unsigned short* Pw = &Pl[w][0];

  const int lrow = lane >> 3;
  const int g0s  = (lane & 7) ^ lrow;
  const int x7   = l16 & 7;

  bf16x8 qf[2];
  {
    const unsigned short* qp = Q + qbase + (size_t)qload * 512 + quad * 8;
    qf[0] = *(const bf16x8*)(qp);
    qf[1] = *(const bf16x8*)(qp + 32);
  }

  float mi = -3e38f, li = 0.f;
  f32x4 ot[4];
  #pragma unroll
  for (int f = 0; f < 4; f++) ot[f] = f32x4{0.f,0.f,0.f,0.f};

  int klo = 0, khi = S2_ - 1;
  if (q0wg + 63 < L2) {
    if (!backward) khi = q0wg + 63;
    else { klo = q0wg; khi = L2 - 1; }
  }

  for (int kt0 = klo; kt0 <= khi; kt0 += 64) {
    #pragma unroll
    for (int c = 0; c < 2; c++) {
      int r = w*16 + c*8 + lrow;
      int kr = kt0 + r; if (kr > S2_-1) kr = S2_-1;
      glds16(Kx + kbase + (size_t)kr * 1024 + g0s * 8, &Kl[(w*16 + c*8) * 64]);
      glds16(VT + vtbase + (size_t)r * 1024 + kt0 + g0s * 8, &Vl[(w*16 + c*8) * 64]);
    }
    __syncthreads();

    bf16x8 kf[4][2], vf[4][2];
    #pragma unroll
    for (int sub = 0; sub < 4; sub++) {
      const unsigned short* kp = &Kl[(sub*16 + l16) * 64];
      kf[sub][0] = *(const bf16x8*)(kp + (( quad      ^ x7) * 8));
      kf[sub][1] = *(const bf16x8*)(kp + (((quad + 4) ^ x7) * 8));
    }
    #pragma unroll
    for (int f = 0; f < 4; f++) {
      const unsigned short* vp = &Vl[(f*16 + l16) * 64];
      vf[f][0] = *(const bf16x8*)(vp + (( quad      ^ x7) * 8));
      vf[f][1] = *(const bf16x8*)(vp + (((quad + 4) ^ x7) * 8));
    }

    f32x4 st[4];
    #pragma unroll
    for (int sub = 0; sub < 4; sub++) {
      f32x4 s = f32x4{0.f,0.f,0.f,0.f};
      s = __builtin_amdgcn_mfma_f32_16x16x32_bf16(kf[sub][0], qf[0], s, 0, 0, 0);
      s = __builtin_amdgcn_mfma_f32_16x16x32_bf16(kf[sub][1], qf[1], s, 0, 0, 0);
      st[sub] = s;
    }

    #pragma unroll
    for (int sub = 0; sub < 4; sub++) {
      #pragma unroll
      for (int r = 0; r < 4; r++) {
        int kg = kt0 + sub*16 + quad*4 + r;
        bool ok;
        if (!backward) ok = (kg < S2_) && ((qg >= L2) || (kg <= qg));
        else           ok = (kg < S2_) && ((qg >= L2) || ((kg >= qg) && (kg < L2)));
        if (!ok) st[sub][r] = -3e38f;
      }
    }

    float mx = -3e38f;
    #pragma unroll
    for (int sub = 0; sub < 4; sub++)
      #pragma unroll
      for (int r = 0; r < 4; r++) mx = fmaxf(mx, st[sub][r]);
    mx = fmaxf(mx, __shfl_xor(mx, 16));
    mx = fmaxf(mx, __shfl_xor(mx, 32));
    float mn = fmaxf(mi, mx);
    float alpha = __expf(mi - mn);
    mi = mn;
    float rs = 0.f;
    #pragma unroll
    for (int sub = 0; sub < 4; sub++)
      #pragma unroll
      for (int r = 0; r < 4; r++) {
        float p = __expf(st[sub][r] - mn);
        st[sub][r] = p; rs += p;
      }
    rs += __shfl_xor(rs, 16);
    rs += __shfl_xor(rs, 32);
    li = li * alpha + rs;
    #pragma unroll
    for (int f = 0; f < 4; f++)
      #pragma unroll
      for (int r = 0; r < 4; r++) ot[f][r] *= alpha;

    #pragma unroll
    for (int sub = 0; sub < 4; sub++) {
      ushort4 pk;
      pk.x = f2bf(st[sub][0]); pk.y = f2bf(st[sub][1]);
      pk.z = f2bf(st[sub][2]); pk.w = f2bf(st[sub][3]);
      *(ushort4*)&Pw[l16*PSTR + sub*16 + quad*4] = pk;
    }
    bf16x8 pfr0 = *(const bf16x8*)&Pw[l16*PSTR +      quad*8];
    bf16x8 pfr1 = *(const bf16x8*)&Pw[l16*PSTR + 32 + quad*8];

    #pragma unroll
    for (int f = 0; f < 4; f++) {
      ot[f] = __builtin_amdgcn_mfma_f32_16x16x32_bf16(vf[f][0], pfr0, ot[f], 0, 0, 0);
      ot[f] = __builtin_amdgcn_mfma_f32_16x16x32_bf16(vf[f][1], pfr1, ot[f], 0, 0, 0);
    }
    __syncthreads();
  }

  if (qg < S2_) {
    float rcp = 1.f / li;
    #pragma unroll
    for (int f = 0; f < 4; f++) {
      ushort4 pk;
      pk.x = f2bf(ot[f][0] * rcp); pk.y = f2bf(ot[f][1] * rcp);
      pk.z = f2bf(ot[f][2] * rcp); pk.w = f2bf(ot[f][3] * rcp);
      *(ushort4*)&CTX[qbase + (size_t)qg * 512 + f*16 + quad*4] = pk;
    }
  }
}

// ----------------------------------------------------------------
extern "C" void kernel_launch(void* const* d_in, const int* in_sizes, int n_in,
                              void* d_out, int out_size, void* d_ws, size_t ws_size,
                              hipStream_t stream)
{
  const float* hidden = (const float*)d_in[0];
  const int*   lens   = (const int*)d_in[1];
  const float* fw[14]; for (int i = 0; i < 14; i++) fw[i] = (const float*)d_in[2 + i];
  const float* bw[14]; for (int i = 0; i < 14; i++) bw[i] = (const float*)d_in[16 + i];
  const float* attn_g = (const float*)d_in[30];
  const float* attn_b = (const float*)d_in[31];
  const float* o_w1 = (const float*)d_in[32];
  const float* o_b1 = (const float*)d_in[33];
  const float* o_w2 = (const float*)d_in[34];
  const float* o_b2 = (const float*)d_in[35];
  const float* o_lng = (const float*)d_in[36];
  const float* o_lnb = (const float*)d_in[37];

  char* ws = (char*)d_ws;
  size_t off = 0;
  auto alloc = [&](size_t bytes)->char* {
    off = (off + 255) & ~(size_t)255;
    char* p = ws + off; off += bytes; return p;
  };

  unsigned short* fw1t = (unsigned short*)alloc((size_t)1024*1024*2);
  unsigned short* fw2t = (unsigned short*)alloc((size_t)512*1024*2);
  unsigned short* fqt  = (unsigned short*)alloc((size_t)512*512*2);
  unsigned short* fkvt = (unsigned short*)alloc((size_t)1024*512*2);  // [K(512 rows); V(512 rows)]
  unsigned short* fot  = (unsigned short*)alloc((size_t)512*512*2);
  unsigned short* bw1t = (unsigned short*)alloc((size_t)1024*1024*2);
  unsigned short* bw2t = (unsigned short*)alloc((size_t)512*1024*2);
  unsigned short* bqt  = (unsigned short*)alloc((size_t)512*512*2);
  unsigned short* bkvt = (unsigned short*)alloc((size_t)1024*512*2);
  unsigned short* bot  = (unsigned short*)alloc((size_t)512*512*2);
  unsigned short* ow1t = (unsigned short*)alloc((size_t)1024*1024*2);
  unsigned short* ow2t = (unsigned short*)alloc((size_t)1024*1024*2);
  float*          biasKV = (float*)alloc(2048*4);

  unsigned short* Xb   = (unsigned short*)alloc((size_t)M_*1024*2);
  unsigned short* big1 = (unsigned short*)alloc((size_t)2*PAD_*1024*2);
  float*          big2 = (float*)alloc((size_t)2*PAD_*512*4);
  unsigned short* LQCT = (unsigned short*)alloc((size_t)2*PAD_*512*2);
  unsigned short* Q2   = (unsigned short*)alloc((size_t)2*PAD_*512*2);

  unsigned short* H12 = big1, *KV2 = big1, *H1o = big1;
  // big2 partitions: [0 .. 2*VTS_) = T12b (bf16) then VT2 (bf16);
  //                  [2*VTS_ .. 4*VTS_) = P2b (bf16 out-proj). Exactly fills big2.
  unsigned short* T12b = (unsigned short*)big2;
  unsigned short* VT2  = (unsigned short*)big2;
  unsigned short* P2b  = (unsigned short*)big2 + 2*VTS_;
  unsigned short* LQ2 = LQCT, *CT2 = LQCT;

  lma_prep_x<<<M_, 256, 0, stream>>>(hidden, Xb);

  {
    TPack tp;
    const float* srcs[14] = { fw[0], fw[2], fw[6], fw[8], fw[10], fw[12],
                              bw[0], bw[2], bw[6], bw[8], bw[10], bw[12],
                              o_w1, o_w2 };
    unsigned short* dsts[14] = { fw1t, fw2t, fqt, fkvt, fkvt + (size_t)512*512, fot,
                                 bw1t, bw2t, bqt, bkvt, bkvt + (size_t)512*512, bot,
                                 ow1t, ow2t };
    int Ks[14] = {1024,1024,512,512,512,512, 1024,1024,512,512,512,512, 1024,1024};
    int Ns[14] = {1024, 512,512,512,512,512, 1024, 512,512,512,512,512, 1024,1024};
    for (int i = 0; i < 14; i++){ tp.src[i]=srcs[i]; tp.dst[i]=dsts[i]; tp.K[i]=Ks[i]; tp.N[i]=Ns[i]; }
    lma_transpose_all<<<dim3(32, 32, 14), 256, 0, stream>>>(tp);
  }
  lma_biascat<<<8, 256, 0, stream>>>(fw[9], fw[11], bw[9], bw[11], biasKV);

  auto G = [&](const unsigned short* A, int lda,
               const unsigned short* B0, const unsigned short* B1,
               const float* b0, const float* b1,
               void* C, int ldc, int M, int N, int K, int mode, int amap){
    int nmt = (M + 127) / 128;
    lma_gemm2<<<dim3(nmt * (N/128)), 256, 0, stream>>>(A, lda, B0, B1, b0, b1, C, ldc, M, N, K, mode, amap, nmt);
  };

  // both-branch FFN + LN + projections (rows<8192 = forward, >=8192 = backward)
  G(Xb, 1024, fw1t, bw1t, fw[1], bw[1], H12, 1024, 2*PAD_, 1024, 1024, 2, 1);  // FFN1+gelu
  G(H12, 1024, fw2t, bw2t, fw[3], bw[3], T12b, 512, 2*PAD_, 512, 1024, 0, 0);  // FFN2 -> bf16
  lma_ln2<<<2*M_, 256, 0, stream>>>(T12b, fw[4], fw[5], bw[4], bw[5], LQ2);
  G(LQ2, 512, fqt, bqt, fw[7], bw[7], Q2, 512, 2*PAD_, 512, 512, 1, 0);        // Q (x0.125)
  G(Xb, 1024, fkvt, bkvt, biasKV, biasKV + 1024, KV2, 1024, 2*PAD_, 1024, 512, 0, 2); // K|V
  lma_vt2<<<dim3(32, 16, 16), 256, 0, stream>>>(KV2, VT2);

  lma_attn4<<<dim3(2048), 256, 0, stream>>>(Q2, KV2, VT2, CT2, lens);

  G(CT2, 512, fot, bot, fw[13], bw[13], P2b, 512, 2*PAD_, 512, 512, 0, 0);     // out proj -> bf16

  lma_attn_ln<<<M_, 256, 0, stream>>>(P2b, P2b + (size_t)PAD_*512, hidden, attn_g, attn_b, Xb);

  G(Xb, 1024, ow1t, ow1t, o_b1, o_b1, H1o, 1024, M_, 1024, 1024, 2, 0);        // out FFN1+gelu
  G(H1o, 1024, ow2t, ow2t, o_b2, o_b2, (float*)d_out, 1024, M_, 1024, 1024, 4, 0); // out FFN2 -> d_out (remapped)
  lma_ln<<<M_, 256, 0, stream>>>((float*)d_out, o_lng, o_lnb, 1024, nullptr, (float*)d_out);
}